// Round 1
// baseline (458.510 us; speedup 1.0000x reference)
//
#include <hip/hip_runtime.h>
#include <hip/hip_bf16.h>
#include <cstdint>
#include <cstddef>

// RWKV6 TimeMix forward, MI355X. B=2 T=2048 C=1024 H=16 N=64.
#define B_ 2
#define T_ 2048
#define C_ 1024
#define H_ 16
#define NCH 32   // number of chunks in scan
#define CHL 64   // chunk length (NCH*CHL = T_)

typedef unsigned short ushort_t;
typedef __bf16 bf16x8 __attribute__((ext_vector_type(8)));
typedef float f32x4 __attribute__((ext_vector_type(4)));

__device__ __forceinline__ ushort_t f2bf(float f) {
  union { float f; uint32_t u; } x; x.f = f;
  uint32_t r = x.u + 0x7fffu + ((x.u >> 16) & 1u);
  return (ushort_t)(r >> 16);
}

__device__ __forceinline__ void gload16(const void* g, void* l) {
  __builtin_amdgcn_global_load_lds(
      (const __attribute__((address_space(1))) void*)g,
      (__attribute__((address_space(3))) void*)l, 16, 0, 0);
}

// ---------------- batched transpose + f32->bf16 convert -------------------
// out[c][r] = bf16(in[r][c]) for c < Cc, 0 for Cc <= c < Cpad. out is (Cpad x R).
struct TDesc { const float* src; ushort_t* dst; int R, Cc, Cpad; };
struct TArgs { TDesc d[9]; };

__global__ __launch_bounds__(256) void transpose_cvt(TArgs args) {
  TDesc D = args.d[blockIdx.z];
  int c0 = blockIdx.x * 32, r0 = blockIdx.y * 32;
  if (c0 >= D.Cpad || r0 >= D.R) return;
  __shared__ float tile[32][33];
  int tx = threadIdx.x & 31, ty = threadIdx.x >> 5;
#pragma unroll
  for (int i = 0; i < 32; i += 8) {
    int r = r0 + ty + i, c = c0 + tx;
    tile[ty + i][tx] = (r < D.R && c < D.Cc) ? D.src[(size_t)r * D.Cc + c] : 0.f;
  }
  __syncthreads();
#pragma unroll
  for (int i = 0; i < 32; i += 8) {
    int c = c0 + ty + i, r = r0 + tx;
    if (c < D.Cpad && r < D.R) D.dst[(size_t)c * D.R + r] = f2bf(tile[tx][ty + i]);
  }
}

// ---------------- prep: xx = shift(x)-x ; xxx = x + xx*tmx (bf16) ---------
__global__ __launch_bounds__(256) void prep_kernel(
    const float* __restrict__ x, const float* __restrict__ tmx,
    float* __restrict__ xx, ushort_t* __restrict__ xxx) {
  size_t idx = ((size_t)blockIdx.x * 256 + threadIdx.x) * 4;
  int tt = (int)((idx >> 10) & (T_ - 1));
  int c = (int)(idx & (C_ - 1));
  float4 xv = *(const float4*)&x[idx];
  float4 xp;
  if (tt == 0) { xp.x = xp.y = xp.z = xp.w = 0.f; }
  else xp = *(const float4*)&x[idx - C_];
  float4 tm = *(const float4*)&tmx[c];
  float4 d;
  d.x = xp.x - xv.x; d.y = xp.y - xv.y; d.z = xp.z - xv.z; d.w = xp.w - xv.w;
  *(float4*)&xx[idx] = d;
  xxx[idx + 0] = f2bf(xv.x + d.x * tm.x);
  xxx[idx + 1] = f2bf(xv.y + d.y * tm.y);
  xxx[idx + 2] = f2bf(xv.z + d.z * tm.z);
  xxx[idx + 3] = f2bf(xv.w + d.w * tm.w);
}

// ---------------- bf16 MFMA GEMM, C = A (MxK) * Bt^T (Bt is NxK) ----------
// m97-style: 128x128 tile, BK=32, 4 waves 2x2, global_load_lds width 16.
// EPI: 0 = f32 store, 1 = silu->f32, 2 = tanh->bf16, 3 = mix->bf16, 4 = decay->f32
template <int EPI>
__global__ __launch_bounds__(256) void gemm_bt(
    const ushort_t* __restrict__ A, int lda,
    const ushort_t* __restrict__ Bt, int ldb,
    void* __restrict__ Cp, int ldc, int K,
    const float* __restrict__ aux0, const float* __restrict__ aux1,
    const float* __restrict__ aux2) {
  __shared__ ushort_t sA[128 * 32];
  __shared__ ushort_t sB[128 * 32];
  const int t = threadIdx.x;
  const int l = t & 63;
  const int w = t >> 6;
  const int wm = w >> 1, wn = w & 1;
  const int m0 = blockIdx.x * 128, n0 = blockIdx.y * 128;
  const int lr = l & 15;
  const int lk = (l >> 4) * 8;

  f32x4 acc[4][4] = {};

  for (int kt = 0; kt < K; kt += 32) {
    __syncthreads();
#pragma unroll
    for (int it = 0; it < 2; ++it) {
      int cbase = it * 256 + w * 64;
      int ca = cbase + l;
      int row = ca >> 2, kc = ca & 3;
      gload16(A + (size_t)(m0 + row) * lda + kt + kc * 8, (char*)sA + (size_t)cbase * 16);
      gload16(Bt + (size_t)(n0 + row) * ldb + kt + kc * 8, (char*)sB + (size_t)cbase * 16);
    }
    __syncthreads();
    bf16x8 af[4], bfr[4];
#pragma unroll
    for (int mi = 0; mi < 4; ++mi)
      af[mi] = *(const bf16x8*)&sA[(wm * 64 + mi * 16 + lr) * 32 + lk];
#pragma unroll
    for (int ni = 0; ni < 4; ++ni)
      bfr[ni] = *(const bf16x8*)&sB[(wn * 64 + ni * 16 + lr) * 32 + lk];
#pragma unroll
    for (int mi = 0; mi < 4; ++mi)
#pragma unroll
      for (int ni = 0; ni < 4; ++ni)
        acc[mi][ni] = __builtin_amdgcn_mfma_f32_16x16x32_bf16(af[mi], bfr[ni], acc[mi][ni], 0, 0, 0);
  }
  // epilogue: C/D layout col = lane&15, row = (lane>>4)*4 + reg (m89-verified)
#pragma unroll
  for (int mi = 0; mi < 4; ++mi) {
#pragma unroll
    for (int ni = 0; ni < 4; ++ni) {
      int col = n0 + wn * 64 + ni * 16 + lr;
#pragma unroll
      for (int r = 0; r < 4; ++r) {
        int row = m0 + wm * 64 + mi * 16 + (l >> 4) * 4 + r;
        float v = acc[mi][ni][r];
        size_t idx = (size_t)row * ldc + col;
        if constexpr (EPI == 0) {
          ((float*)Cp)[idx] = v;
        } else if constexpr (EPI == 1) {
          ((float*)Cp)[idx] = v / (1.f + expf(-v));
        } else if constexpr (EPI == 2) {
          ((ushort_t*)Cp)[idx] = f2bf(tanhf(v));
        } else if constexpr (EPI == 3) {
          size_t xi = (size_t)row * C_ + col;
          ((ushort_t*)Cp)[idx] = f2bf(aux0[xi] + aux1[xi] * (aux2[col] + v));
        } else if constexpr (EPI == 4) {
          ((float*)Cp)[idx] = expf(-expf(aux2[col] + v));
        }
      }
    }
  }
}

// ---------------- ruk[b,t,h] = sum_i r*u*k ---------------------------------
__global__ __launch_bounds__(256) void ruk_kernel(
    const float* __restrict__ rx, const float* __restrict__ kx,
    const float* __restrict__ u, float* __restrict__ ruk) {
  int bt = blockIdx.x;
  int w = threadIdx.x >> 6, l = threadIdx.x & 63;
#pragma unroll
  for (int hh = 0; hh < 4; ++hh) {
    int h = w * 4 + hh;
    size_t o = (size_t)bt * C_ + h * 64 + l;
    float s = rx[o] * kx[o] * u[h * 64 + l];
#pragma unroll
    for (int off = 32; off; off >>= 1) s += __shfl_xor(s, off);
    if (l == 0) ruk[(size_t)bt * H_ + h] = s;
  }
}

// ---------------- scan pass1: per-chunk M, P -------------------------------
// block = (chunk, bh), 256 thr: ig = tid>>6 owns rows i in [ig*16, ig*16+16), j = lane
__global__ __launch_bounds__(256) void scan_pass1(
    const float* __restrict__ kx, const float* __restrict__ vx,
    const float* __restrict__ dx, float* __restrict__ Mo, float* __restrict__ Po) {
  int ch = blockIdx.x, bh = blockIdx.y;
  int b = bh >> 4, h = bh & 15;
  int tid = threadIdx.x, ig = tid >> 6, j = tid & 63;
  size_t base = ((size_t)b * T_ + (size_t)ch * CHL) * C_ + h * 64;
  float m[16];
#pragma unroll
  for (int ii = 0; ii < 16; ++ii) m[ii] = 0.f;
  for (int t = 0; t < CHL; ++t) {
    size_t o = base + (size_t)t * C_;
    float vj = vx[o + j];
    const float4* kp = (const float4*)(kx + o + ig * 16);
    const float4* dp = (const float4*)(dx + o + ig * 16);
#pragma unroll
    for (int q = 0; q < 4; ++q) {
      float4 kq = kp[q], dq = dp[q];
      m[q * 4 + 0] = dq.x * m[q * 4 + 0] + kq.x * vj;
      m[q * 4 + 1] = dq.y * m[q * 4 + 1] + kq.y * vj;
      m[q * 4 + 2] = dq.z * m[q * 4 + 2] + kq.z * vj;
      m[q * 4 + 3] = dq.w * m[q * 4 + 3] + kq.w * vj;
    }
  }
  float* Mrow = Mo + (size_t)(ch * 32 + bh) * 4096;
#pragma unroll
  for (int ii = 0; ii < 16; ++ii) Mrow[(ig * 16 + ii) * 64 + j] = m[ii];
  if (tid < 64) {
    float p = 1.f;
    for (int t = 0; t < CHL; ++t) p *= dx[base + (size_t)t * C_ + tid];
    Po[(size_t)(ch * 32 + bh) * 64 + tid] = p;
  }
}

// ---------------- combine: chunk-start states ------------------------------
__global__ __launch_bounds__(256) void scan_combine(
    const float* __restrict__ Mo, const float* __restrict__ Po, float* __restrict__ S0) {
  int bh = blockIdx.x >> 4;
  int ij = (blockIdx.x & 15) * 256 + threadIdx.x;
  int i = ij >> 6;
  float s = 0.f;
  for (int c = 0; c < NCH; ++c) {
    size_t o = (size_t)(c * 32 + bh) * 4096 + ij;
    S0[o] = s;
    s = Po[(size_t)(c * 32 + bh) * 64 + i] * s + Mo[o];
  }
}

// ---------------- scan pass2: replay chunk from start state, emit y --------
__global__ __launch_bounds__(256) void scan_pass2(
    const float* __restrict__ rx, const float* __restrict__ kx,
    const float* __restrict__ vx, const float* __restrict__ dx,
    const float* __restrict__ ruk, const float* __restrict__ S0,
    float* __restrict__ yo) {
  int ch = blockIdx.x, bh = blockIdx.y;
  int b = bh >> 4, h = bh & 15;
  int tid = threadIdx.x, ig = tid >> 6, j = tid & 63;
  __shared__ float part[4][64];
  size_t base = ((size_t)b * T_ + (size_t)ch * CHL) * C_ + h * 64;
  const float* Sb = S0 + (size_t)(ch * 32 + bh) * 4096;
  float S[16];
#pragma unroll
  for (int ii = 0; ii < 16; ++ii) S[ii] = Sb[(ig * 16 + ii) * 64 + j];
  for (int t = 0; t < CHL; ++t) {
    size_t o = base + (size_t)t * C_;
    float vj = vx[o + j];
    const float4* rp = (const float4*)(rx + o + ig * 16);
    const float4* kp = (const float4*)(kx + o + ig * 16);
    const float4* dp = (const float4*)(dx + o + ig * 16);
    float yp = 0.f;
#pragma unroll
    for (int q = 0; q < 4; ++q) {
      float4 rq = rp[q], kq = kp[q], dq = dp[q];
      yp += rq.x * S[q * 4 + 0]; S[q * 4 + 0] = dq.x * S[q * 4 + 0] + kq.x * vj;
      yp += rq.y * S[q * 4 + 1]; S[q * 4 + 1] = dq.y * S[q * 4 + 1] + kq.y * vj;
      yp += rq.z * S[q * 4 + 2]; S[q * 4 + 2] = dq.z * S[q * 4 + 2] + kq.z * vj;
      yp += rq.w * S[q * 4 + 3]; S[q * 4 + 3] = dq.w * S[q * 4 + 3] + kq.w * vj;
    }
    part[ig][j] = yp;
    __syncthreads();
    if (ig == 0) {
      float rukt = ruk[((size_t)b * T_ + (size_t)ch * CHL + t) * H_ + h];
      yo[o + j] = part[0][j] + part[1][j] + part[2][j] + part[3][j] + rukt * vj;
    }
    __syncthreads();
  }
}

// ---------------- GroupNorm(H groups) * g -> bf16 Z ------------------------
__global__ __launch_bounds__(256) void gn_kernel(
    const float* __restrict__ y, const float* __restrict__ g,
    const float* __restrict__ lnw, const float* __restrict__ lnb,
    ushort_t* __restrict__ Z) {
  int blk = blockIdx.x;            // B*T*4
  int bt = blk >> 2, hq = blk & 3;
  int w = threadIdx.x >> 6, l = threadIdx.x & 63;
  int h = hq * 4 + w;
  size_t o = (size_t)bt * C_ + h * 64 + l;
  float v = y[o];
  float s = v, s2 = v * v;
#pragma unroll
  for (int off = 32; off; off >>= 1) { s += __shfl_xor(s, off); s2 += __shfl_xor(s2, off); }
  float mu = s * (1.f / 64.f);
  float var = s2 * (1.f / 64.f) - mu * mu;
  float yn = (v - mu) * rsqrtf(var + 6.4e-4f);   // EPS = 1e-5 * 64
  Z[o] = f2bf((yn * lnw[h * 64 + l] + lnb[h * 64 + l]) * g[o]);
}

// ===========================================================================
extern "C" void kernel_launch(void* const* d_in, const int* in_sizes, int n_in,
                              void* d_out, int out_size, void* d_ws, size_t ws_size,
                              hipStream_t stream) {
  const float* x    = (const float*)d_in[0];
  const float* tmx  = (const float*)d_in[1];
  const float* tmw  = (const float*)d_in[2];
  const float* tmk  = (const float*)d_in[3];
  const float* tmv  = (const float*)d_in[4];
  const float* tmr  = (const float*)d_in[5];
  const float* tmg  = (const float*)d_in[6];
  const float* maaw1 = (const float*)d_in[7];
  const float* maaw2 = (const float*)d_in[8];
  const float* tdec = (const float*)d_in[9];
  const float* tdw1 = (const float*)d_in[10];
  const float* tdw2 = (const float*)d_in[11];
  const float* u    = (const float*)d_in[12];
  const float* Wr   = (const float*)d_in[13];
  const float* Wk   = (const float*)d_in[14];
  const float* Wv   = (const float*)d_in[15];
  const float* Wg   = (const float*)d_in[16];
  const float* Wo   = (const float*)d_in[17];
  const float* lnw  = (const float*)d_in[18];
  const float* lnb  = (const float*)d_in[19];

  char* ws = (char*)d_ws;
  const size_t MB = 1ull << 20;
  float*    xx     = (float*)(ws + 0);            // 16MB   (reused later: y)
  ushort_t* xxx    = (ushort_t*)(ws + 16 * MB);   // 8MB    (reused later: Z)
  ushort_t* WrT    = (ushort_t*)(ws + 24 * MB);
  ushort_t* WkT    = (ushort_t*)(ws + 26 * MB);
  ushort_t* WvT    = (ushort_t*)(ws + 28 * MB);
  ushort_t* WgT    = (ushort_t*)(ws + 30 * MB);
  ushort_t* WoT    = (ushort_t*)(ws + 32 * MB);
  ushort_t* maaW1T = (ushort_t*)(ws + 34 * MB);            // 256x1024
  ushort_t* maaW2T = (ushort_t*)(ws + 34 * MB + 512 * 1024); // 1024x160
  ushort_t* tdW1T  = (ushort_t*)(ws + 35 * MB);            // 128x1024
  ushort_t* tdW2T  = (ushort_t*)(ws + 35 * MB + 256 * 1024); // 1024x64
  ushort_t* t5     = (ushort_t*)(ws + 36 * MB);   // 4096x256 bf16
  ushort_t* t5d    = (ushort_t*)(ws + 38 * MB);   // 4096x128 bf16
  ushort_t* Xm[5];
  for (int f = 0; f < 5; ++f) Xm[f] = (ushort_t*)(ws + 40 * MB + (size_t)f * 8 * MB);
  float* Mbuf = (float*)(ws + 40 * MB);  // 16MB, reuse of Xm[0..1] after last read
  float* S0b  = (float*)(ws + 57 * MB);  // 16MB, reuse of Xm[2..3] after last read
  float* rb   = (float*)(ws + 80 * MB);
  float* kb   = (float*)(ws + 96 * MB);
  float* vb   = (float*)(ws + 112 * MB);
  float* gb   = (float*)(ws + 128 * MB);
  float* dec  = (float*)(ws + 144 * MB);
  float* ruk  = (float*)(ws + 160 * MB);
  float* Pbuf = (float*)(ws + 160 * MB + 512 * 1024);
  float* yb   = (float*)(ws + 0);              // alias xx (dead by then)
  ushort_t* Zb = (ushort_t*)(ws + 16 * MB);    // alias xxx (dead by then)

  // 1) weight transposes/converts (9 matrices in one launch)
  TArgs ta;
  ta.d[0] = TDesc{Wr,    WrT,    1024, 1024, 1024};
  ta.d[1] = TDesc{Wk,    WkT,    1024, 1024, 1024};
  ta.d[2] = TDesc{Wv,    WvT,    1024, 1024, 1024};
  ta.d[3] = TDesc{Wg,    WgT,    1024, 1024, 1024};
  ta.d[4] = TDesc{Wo,    WoT,    1024, 1024, 1024};
  ta.d[5] = TDesc{maaw1, maaW1T, 1024, 160,  256};
  ta.d[6] = TDesc{tdw1,  tdW1T,  1024, 64,   128};
  ta.d[7] = TDesc{tdw2,  tdW2T,  64,   1024, 1024};
  ta.d[8] = TDesc{maaw2, maaW2T, 160,  1024, 1024};
  transpose_cvt<<<dim3(32, 32, 9), 256, 0, stream>>>(ta);

  // 2) token shift + base mix
  prep_kernel<<<(B_ * T_ * C_) / 1024, 256, 0, stream>>>(x, tmx, xx, xxx);

  // 3) t5 = tanh(xxx @ maa_w1)  (M=4096, N=256pad, K=1024) -> bf16
  gemm_bt<2><<<dim3(32, 2), 256, 0, stream>>>(xxx, C_, maaW1T, C_, t5, 256, C_,
                                              nullptr, nullptr, nullptr);

  // 4) per-f mix: Xm[f] = bf16(x + xx*(tm_f + t5_f @ maa_w2_f))  (K=32)
  const float* tmvec[5] = {tmw, tmk, tmv, tmr, tmg};
  for (int f = 0; f < 5; ++f)
    gemm_bt<3><<<dim3(32, 8), 256, 0, stream>>>(t5 + f * 32, 256, maaW2T + f * 32, 160,
                                                Xm[f], C_, 32, x, xx, tmvec[f]);

  // 5) projections r,k,v,g  (M=4096, N=1024, K=1024)
  gemm_bt<0><<<dim3(32, 8), 256, 0, stream>>>(Xm[3], C_, WrT, C_, rb, C_, C_, nullptr, nullptr, nullptr);
  gemm_bt<0><<<dim3(32, 8), 256, 0, stream>>>(Xm[1], C_, WkT, C_, kb, C_, C_, nullptr, nullptr, nullptr);
  gemm_bt<0><<<dim3(32, 8), 256, 0, stream>>>(Xm[2], C_, WvT, C_, vb, C_, C_, nullptr, nullptr, nullptr);
  gemm_bt<1><<<dim3(32, 8), 256, 0, stream>>>(Xm[4], C_, WgT, C_, gb, C_, C_, nullptr, nullptr, nullptr);

  // 6) decay: t5d = tanh(xw @ td_w1); dec = exp(-exp(tdecay + t5d @ td_w2))
  gemm_bt<2><<<dim3(32, 1), 256, 0, stream>>>(Xm[0], C_, tdW1T, C_, t5d, 128, C_,
                                              nullptr, nullptr, nullptr);
  gemm_bt<4><<<dim3(32, 8), 256, 0, stream>>>(t5d, 128, tdW2T, 64, dec, C_, 64,
                                              nullptr, nullptr, tdec);

  // 7) scan (chunked, 3 phases) + bonus-term dot
  ruk_kernel<<<B_ * T_, 256, 0, stream>>>(rb, kb, u, ruk);
  scan_pass1<<<dim3(NCH, B_ * H_), 256, 0, stream>>>(kb, vb, dec, Mbuf, Pbuf);
  scan_combine<<<512, 256, 0, stream>>>(Mbuf, Pbuf, S0b);
  scan_pass2<<<dim3(NCH, B_ * H_), 256, 0, stream>>>(rb, kb, vb, dec, ruk, S0b, yb);

  // 8) GroupNorm * gate -> bf16
  gn_kernel<<<B_ * T_ * 4, 256, 0, stream>>>(yb, gb, lnw, lnb, Zb);

  // 9) out = Z @ Wo  (f32)
  gemm_bt<0><<<dim3(32, 8), 256, 0, stream>>>(Zb, C_, WoT, C_, (float*)d_out, C_, C_,
                                              nullptr, nullptr, nullptr);
}

// Round 2
// 401.086 us; speedup vs baseline: 1.1432x; 1.1432x over previous
//
#include <hip/hip_runtime.h>
#include <hip/hip_bf16.h>
#include <cstdint>
#include <cstddef>

// RWKV6 TimeMix forward, MI355X. B=2 T=2048 C=1024 H=16 N=64.
#define B_ 2
#define T_ 2048
#define C_ 1024
#define H_ 16
#define NCH 64   // number of chunks in scan
#define CHL 32   // chunk length (NCH*CHL = T_)

typedef unsigned short ushort_t;
typedef __bf16 bf16x8 __attribute__((ext_vector_type(8)));
typedef float f32x4 __attribute__((ext_vector_type(4)));

__device__ __forceinline__ ushort_t f2bf(float f) {
  union { float f; uint32_t u; } x; x.f = f;
  uint32_t r = x.u + 0x7fffu + ((x.u >> 16) & 1u);
  return (ushort_t)(r >> 16);
}

__device__ __forceinline__ void gload16(const void* g, void* l) {
  __builtin_amdgcn_global_load_lds(
      (const __attribute__((address_space(1))) void*)g,
      (__attribute__((address_space(3))) void*)l, 16, 0, 0);
}

// ---------------- batched transpose + f32->bf16 convert -------------------
struct TDesc { const float* src; ushort_t* dst; int R, Cc, Cpad; };
struct TArgs { TDesc d[9]; };

__global__ __launch_bounds__(256) void transpose_cvt(TArgs args) {
  TDesc D = args.d[blockIdx.z];
  int c0 = blockIdx.x * 32, r0 = blockIdx.y * 32;
  if (c0 >= D.Cpad || r0 >= D.R) return;
  __shared__ float tile[32][33];
  int tx = threadIdx.x & 31, ty = threadIdx.x >> 5;
#pragma unroll
  for (int i = 0; i < 32; i += 8) {
    int r = r0 + ty + i, c = c0 + tx;
    tile[ty + i][tx] = (r < D.R && c < D.Cc) ? D.src[(size_t)r * D.Cc + c] : 0.f;
  }
  __syncthreads();
#pragma unroll
  for (int i = 0; i < 32; i += 8) {
    int c = c0 + ty + i, r = r0 + tx;
    if (c < D.Cpad && r < D.R) D.dst[(size_t)c * D.R + r] = f2bf(tile[tx][ty + i]);
  }
}

// ---------------- prep: xx = shift(x)-x ; xxx = x + xx*tmx (bf16) ---------
__global__ __launch_bounds__(256) void prep_kernel(
    const float* __restrict__ x, const float* __restrict__ tmx,
    float* __restrict__ xx, ushort_t* __restrict__ xxx) {
  size_t idx = ((size_t)blockIdx.x * 256 + threadIdx.x) * 4;
  int tt = (int)((idx >> 10) & (T_ - 1));
  int c = (int)(idx & (C_ - 1));
  float4 xv = *(const float4*)&x[idx];
  float4 xp;
  if (tt == 0) { xp.x = xp.y = xp.z = xp.w = 0.f; }
  else xp = *(const float4*)&x[idx - C_];
  float4 tm = *(const float4*)&tmx[c];
  float4 d;
  d.x = xp.x - xv.x; d.y = xp.y - xv.y; d.z = xp.z - xv.z; d.w = xp.w - xv.w;
  *(float4*)&xx[idx] = d;
  xxx[idx + 0] = f2bf(xv.x + d.x * tm.x);
  xxx[idx + 1] = f2bf(xv.y + d.y * tm.y);
  xxx[idx + 2] = f2bf(xv.z + d.z * tm.z);
  xxx[idx + 3] = f2bf(xv.w + d.w * tm.w);
}

// ---------------- bf16 MFMA GEMM, C = A (MxK) * Bt^T (Bt is NxK) ----------
// EPI: 0 = f32 store, 1 = silu->f32, 2 = tanh->bf16, 4 = decay->f32
template <int EPI>
__global__ __launch_bounds__(256) void gemm_bt(
    const ushort_t* __restrict__ A, int lda,
    const ushort_t* __restrict__ Bt, int ldb,
    void* __restrict__ Cp, int ldc, int K,
    const float* __restrict__ aux2) {
  __shared__ ushort_t sA[128 * 32];
  __shared__ ushort_t sB[128 * 32];
  const int t = threadIdx.x;
  const int l = t & 63;
  const int w = t >> 6;
  const int wm = w >> 1, wn = w & 1;
  const int m0 = blockIdx.x * 128, n0 = blockIdx.y * 128;
  const int lr = l & 15;
  const int lk = (l >> 4) * 8;

  f32x4 acc[4][4] = {};

  for (int kt = 0; kt < K; kt += 32) {
    __syncthreads();
#pragma unroll
    for (int it = 0; it < 2; ++it) {
      int cbase = it * 256 + w * 64;
      int ca = cbase + l;
      int row = ca >> 2, kc = ca & 3;
      gload16(A + (size_t)(m0 + row) * lda + kt + kc * 8, (char*)sA + (size_t)cbase * 16);
      gload16(Bt + (size_t)(n0 + row) * ldb + kt + kc * 8, (char*)sB + (size_t)cbase * 16);
    }
    __syncthreads();
    bf16x8 af[4], bfr[4];
#pragma unroll
    for (int mi = 0; mi < 4; ++mi)
      af[mi] = *(const bf16x8*)&sA[(wm * 64 + mi * 16 + lr) * 32 + lk];
#pragma unroll
    for (int ni = 0; ni < 4; ++ni)
      bfr[ni] = *(const bf16x8*)&sB[(wn * 64 + ni * 16 + lr) * 32 + lk];
#pragma unroll
    for (int mi = 0; mi < 4; ++mi)
#pragma unroll
      for (int ni = 0; ni < 4; ++ni)
        acc[mi][ni] = __builtin_amdgcn_mfma_f32_16x16x32_bf16(af[mi], bfr[ni], acc[mi][ni], 0, 0, 0);
  }
#pragma unroll
  for (int mi = 0; mi < 4; ++mi) {
#pragma unroll
    for (int ni = 0; ni < 4; ++ni) {
      int col = n0 + wn * 64 + ni * 16 + lr;
#pragma unroll
      for (int r = 0; r < 4; ++r) {
        int row = m0 + wm * 64 + mi * 16 + (l >> 4) * 4 + r;
        float v = acc[mi][ni][r];
        size_t idx = (size_t)row * ldc + col;
        if constexpr (EPI == 0) {
          ((float*)Cp)[idx] = v;
        } else if constexpr (EPI == 1) {
          ((float*)Cp)[idx] = v / (1.f + expf(-v));
        } else if constexpr (EPI == 2) {
          ((ushort_t*)Cp)[idx] = f2bf(tanhf(v));
        } else if constexpr (EPI == 4) {
          ((float*)Cp)[idx] = expf(-expf(aux2[col] + v));
        }
      }
    }
  }
}

// ---------------- batched projections r,k,v,g (z-dim selects) --------------
struct PDesc { const ushort_t* A; const ushort_t* Bt; float* C; int epi; };
struct PArgs { PDesc d[4]; };

__global__ __launch_bounds__(256, 3) void gemm_proj4(PArgs args) {
  PDesc D = args.d[blockIdx.z];
  __shared__ ushort_t sA[128 * 32];
  __shared__ ushort_t sB[128 * 32];
  const int t = threadIdx.x;
  const int l = t & 63;
  const int w = t >> 6;
  const int wm = w >> 1, wn = w & 1;
  const int m0 = blockIdx.x * 128, n0 = blockIdx.y * 128;
  const int lr = l & 15;
  const int lk = (l >> 4) * 8;

  f32x4 acc[4][4] = {};

  for (int kt = 0; kt < C_; kt += 32) {
    __syncthreads();
#pragma unroll
    for (int it = 0; it < 2; ++it) {
      int cbase = it * 256 + w * 64;
      int ca = cbase + l;
      int row = ca >> 2, kc = ca & 3;
      gload16(D.A + (size_t)(m0 + row) * C_ + kt + kc * 8, (char*)sA + (size_t)cbase * 16);
      gload16(D.Bt + (size_t)(n0 + row) * C_ + kt + kc * 8, (char*)sB + (size_t)cbase * 16);
    }
    __syncthreads();
    bf16x8 af[4], bfr[4];
#pragma unroll
    for (int mi = 0; mi < 4; ++mi)
      af[mi] = *(const bf16x8*)&sA[(wm * 64 + mi * 16 + lr) * 32 + lk];
#pragma unroll
    for (int ni = 0; ni < 4; ++ni)
      bfr[ni] = *(const bf16x8*)&sB[(wn * 64 + ni * 16 + lr) * 32 + lk];
#pragma unroll
    for (int mi = 0; mi < 4; ++mi)
#pragma unroll
      for (int ni = 0; ni < 4; ++ni)
        acc[mi][ni] = __builtin_amdgcn_mfma_f32_16x16x32_bf16(af[mi], bfr[ni], acc[mi][ni], 0, 0, 0);
  }
  const int epi = D.epi;
#pragma unroll
  for (int mi = 0; mi < 4; ++mi) {
#pragma unroll
    for (int ni = 0; ni < 4; ++ni) {
      int col = n0 + wn * 64 + ni * 16 + lr;
#pragma unroll
      for (int r = 0; r < 4; ++r) {
        int row = m0 + wm * 64 + mi * 16 + (l >> 4) * 4 + r;
        float v = acc[mi][ni][r];
        if (epi) v = v / (1.f + expf(-v));
        D.C[(size_t)row * C_ + col] = v;
      }
    }
  }
}

// ---------------- fused data-dependent mix (5 outputs, x/xx staged once) ---
// tile: 64 rows x 128 cols. Xm[f] = bf16(x + xx*(tm_f + t5_f @ w2_f)), K=32.
struct MixArgs { const float* tm[5]; ushort_t* dst[5]; };

__global__ __launch_bounds__(256) void fused_mix(
    const float* __restrict__ x, const float* __restrict__ xx,
    const ushort_t* __restrict__ t5, const ushort_t* __restrict__ w2t,
    MixArgs margs) {
  __shared__ float xs[64 * 128];
  __shared__ float xxs[64 * 128];
  __shared__ ushort_t sA[64 * 32];
  __shared__ ushort_t sB[128 * 32];
  const int t = threadIdx.x;
  const int l = t & 63;
  const int w = t >> 6;
  const int wm = w >> 1, wn = w & 1;
  const int m0 = blockIdx.x * 64, n0 = blockIdx.y * 128;
  const int lr = l & 15;
  const int lk = (l >> 4) * 8;

  // stage x/xx tile (f32), 8 rows per iteration
#pragma unroll
  for (int it = 0; it < 8; ++it) {
    int row = it * 8 + (t >> 5);
    int c16 = t & 31;
    gload16(x + (size_t)(m0 + row) * C_ + n0 + c16 * 4, (char*)xs + row * 512 + c16 * 16);
    gload16(xx + (size_t)(m0 + row) * C_ + n0 + c16 * 4, (char*)xxs + row * 512 + c16 * 16);
  }

  for (int f = 0; f < 5; ++f) {
    __syncthreads();   // protect sA/sB from previous iter reads; also drains x/xx staging
    {
      int row = t >> 2, c8 = t & 3;
      gload16(t5 + (size_t)(m0 + row) * 256 + f * 32 + c8 * 8, (char*)sA + t * 16);
    }
#pragma unroll
    for (int it = 0; it < 2; ++it) {
      int row = it * 64 + (t >> 2), c8 = t & 3;
      gload16(w2t + (size_t)(n0 + row) * 160 + f * 32 + c8 * 8,
              (char*)sB + it * 4096 + t * 16);
    }
    __syncthreads();
    bf16x8 af[2], bfr[4];
#pragma unroll
    for (int mi = 0; mi < 2; ++mi)
      af[mi] = *(const bf16x8*)&sA[(wm * 32 + mi * 16 + lr) * 32 + lk];
#pragma unroll
    for (int ni = 0; ni < 4; ++ni)
      bfr[ni] = *(const bf16x8*)&sB[(wn * 64 + ni * 16 + lr) * 32 + lk];
    f32x4 acc[2][4] = {};
#pragma unroll
    for (int mi = 0; mi < 2; ++mi)
#pragma unroll
      for (int ni = 0; ni < 4; ++ni)
        acc[mi][ni] = __builtin_amdgcn_mfma_f32_16x16x32_bf16(af[mi], bfr[ni], acc[mi][ni], 0, 0, 0);
    const float* tmf = margs.tm[f];
    ushort_t* dst = margs.dst[f];
#pragma unroll
    for (int mi = 0; mi < 2; ++mi) {
#pragma unroll
      for (int ni = 0; ni < 4; ++ni) {
        int cl = wn * 64 + ni * 16 + lr;
        int col = n0 + cl;
        float tmv = tmf[col];
#pragma unroll
        for (int r = 0; r < 4; ++r) {
          int rl = wm * 32 + mi * 16 + (l >> 4) * 4 + r;
          int row = m0 + rl;
          float xv = xs[rl * 128 + cl];
          float xxv = xxs[rl * 128 + cl];
          dst[(size_t)row * C_ + col] = f2bf(xv + xxv * (tmv + acc[mi][ni][r]));
        }
      }
    }
  }
}

// ---------------- scan pass1: per-chunk M (64x64) and P (64) ---------------
// block=(chunk,bh), 256 thr: ig=tid>>6 owns rows i in [ig*16,+16), j=lane=column
__global__ __launch_bounds__(256) void scan_pass1(
    const float* __restrict__ kx, const float* __restrict__ vx,
    const float* __restrict__ dx, float* __restrict__ Mo, float* __restrict__ Po) {
  int ch = blockIdx.x, bh = blockIdx.y;
  int b = bh >> 4, h = bh & 15;
  int tid = threadIdx.x, ig = tid >> 6, j = tid & 63;
  size_t base = ((size_t)b * T_ + (size_t)ch * CHL) * C_ + h * 64;
  float m[16], p[16];
#pragma unroll
  for (int ii = 0; ii < 16; ++ii) { m[ii] = 0.f; p[ii] = 1.f; }
  for (int t = 0; t < CHL; ++t) {
    size_t o = base + (size_t)t * C_;
    float vj = vx[o + j];
    const float4* kp = (const float4*)(kx + o + ig * 16);
    const float4* dp = (const float4*)(dx + o + ig * 16);
#pragma unroll
    for (int q = 0; q < 4; ++q) {
      float4 kq = kp[q], dq = dp[q];
      m[q * 4 + 0] = dq.x * m[q * 4 + 0] + kq.x * vj;  p[q * 4 + 0] *= dq.x;
      m[q * 4 + 1] = dq.y * m[q * 4 + 1] + kq.y * vj;  p[q * 4 + 1] *= dq.y;
      m[q * 4 + 2] = dq.z * m[q * 4 + 2] + kq.z * vj;  p[q * 4 + 2] *= dq.z;
      m[q * 4 + 3] = dq.w * m[q * 4 + 3] + kq.w * vj;  p[q * 4 + 3] *= dq.w;
    }
  }
  float* Mrow = Mo + (size_t)(ch * 32 + bh) * 4096;
#pragma unroll
  for (int ii = 0; ii < 16; ++ii) Mrow[(ig * 16 + ii) * 64 + j] = m[ii];
  if (j == 0) {
    float* Pr = Po + (size_t)(ch * 32 + bh) * 64 + ig * 16;
#pragma unroll
    for (int ii = 0; ii < 16; ++ii) Pr[ii] = p[ii];
  }
}

// ---------------- combine: chunk-start states, IN-PLACE over M -------------
__global__ __launch_bounds__(256) void scan_combine(
    float* __restrict__ Mo, const float* __restrict__ Po) {
  int bh = blockIdx.x >> 4;
  int ij = (blockIdx.x & 15) * 256 + threadIdx.x;
  int i = ij >> 6;
  float s = 0.f;
  for (int c = 0; c < NCH; ++c) {
    size_t o = (size_t)(c * 32 + bh) * 4096 + ij;
    float mloc = Mo[o];
    float p = Po[(size_t)(c * 32 + bh) * 64 + i];
    Mo[o] = s;                   // chunk-start state for chunk c
    s = p * s + mloc;
  }
}

// ---------------- scan pass2: replay chunk, y partials in LDS, 1 barrier ---
__global__ __launch_bounds__(256) void scan_pass2(
    const float* __restrict__ rx, const float* __restrict__ kx,
    const float* __restrict__ vx, const float* __restrict__ dx,
    const float* __restrict__ u, const float* __restrict__ S0,
    float* __restrict__ yo) {
  int ch = blockIdx.x, bh = blockIdx.y;
  int b = bh >> 4, h = bh & 15;
  int tid = threadIdx.x, ig = tid >> 6, j = tid & 63;
  __shared__ float part[CHL][4][64];   // 32 KB
  size_t base = ((size_t)b * T_ + (size_t)ch * CHL) * C_ + h * 64;
  const float* Sb = S0 + (size_t)(ch * 32 + bh) * 4096;
  float S[16];
#pragma unroll
  for (int ii = 0; ii < 16; ++ii) S[ii] = Sb[(ig * 16 + ii) * 64 + j];
  const float4* up = (const float4*)(u + h * 64 + ig * 16);
  float4 u4[4];
#pragma unroll
  for (int q = 0; q < 4; ++q) u4[q] = up[q];

  for (int t = 0; t < CHL; ++t) {
    size_t o = base + (size_t)t * C_;
    float vj = vx[o + j];
    const float4* rp = (const float4*)(rx + o + ig * 16);
    const float4* kp = (const float4*)(kx + o + ig * 16);
    const float4* dp = (const float4*)(dx + o + ig * 16);
    float yp = 0.f, rukp = 0.f;
#pragma unroll
    for (int q = 0; q < 4; ++q) {
      float4 rq = rp[q], kq = kp[q], dq = dp[q];
      yp += rq.x * S[q * 4 + 0];  rukp += (rq.x * u4[q].x) * kq.x;
      S[q * 4 + 0] = dq.x * S[q * 4 + 0] + kq.x * vj;
      yp += rq.y * S[q * 4 + 1];  rukp += (rq.y * u4[q].y) * kq.y;
      S[q * 4 + 1] = dq.y * S[q * 4 + 1] + kq.y * vj;
      yp += rq.z * S[q * 4 + 2];  rukp += (rq.z * u4[q].z) * kq.z;
      S[q * 4 + 2] = dq.z * S[q * 4 + 2] + kq.z * vj;
      yp += rq.w * S[q * 4 + 3];  rukp += (rq.w * u4[q].w) * kq.w;
      S[q * 4 + 3] = dq.w * S[q * 4 + 3] + kq.w * vj;
    }
    part[t][ig][j] = yp + rukp * vj;
  }
  __syncthreads();
  int tg = tid >> 6;
  for (int tt = tg * (CHL / 4); tt < (tg + 1) * (CHL / 4); ++tt) {
    yo[base + (size_t)tt * C_ + j] =
        part[tt][0][j] + part[tt][1][j] + part[tt][2][j] + part[tt][3][j];
  }
}

// ---------------- GroupNorm(H groups) * g -> bf16 Z ------------------------
__global__ __launch_bounds__(256) void gn_kernel(
    const float* __restrict__ y, const float* __restrict__ g,
    const float* __restrict__ lnw, const float* __restrict__ lnb,
    ushort_t* __restrict__ Z) {
  int blk = blockIdx.x;            // B*T*4
  int bt = blk >> 2, hq = blk & 3;
  int w = threadIdx.x >> 6, l = threadIdx.x & 63;
  int h = hq * 4 + w;
  size_t o = (size_t)bt * C_ + h * 64 + l;
  float v = y[o];
  float s = v, s2 = v * v;
#pragma unroll
  for (int off = 32; off; off >>= 1) { s += __shfl_xor(s, off); s2 += __shfl_xor(s2, off); }
  float mu = s * (1.f / 64.f);
  float var = s2 * (1.f / 64.f) - mu * mu;
  float yn = (v - mu) * rsqrtf(var + 6.4e-4f);   // EPS = 1e-5 * 64
  Z[o] = f2bf((yn * lnw[h * 64 + l] + lnb[h * 64 + l]) * g[o]);
}

// ===========================================================================
extern "C" void kernel_launch(void* const* d_in, const int* in_sizes, int n_in,
                              void* d_out, int out_size, void* d_ws, size_t ws_size,
                              hipStream_t stream) {
  const float* x    = (const float*)d_in[0];
  const float* tmx  = (const float*)d_in[1];
  const float* tmw  = (const float*)d_in[2];
  const float* tmk  = (const float*)d_in[3];
  const float* tmv  = (const float*)d_in[4];
  const float* tmr  = (const float*)d_in[5];
  const float* tmg  = (const float*)d_in[6];
  const float* maaw1 = (const float*)d_in[7];
  const float* maaw2 = (const float*)d_in[8];
  const float* tdec = (const float*)d_in[9];
  const float* tdw1 = (const float*)d_in[10];
  const float* tdw2 = (const float*)d_in[11];
  const float* u    = (const float*)d_in[12];
  const float* Wr   = (const float*)d_in[13];
  const float* Wk   = (const float*)d_in[14];
  const float* Wv   = (const float*)d_in[15];
  const float* Wg   = (const float*)d_in[16];
  const float* Wo   = (const float*)d_in[17];
  const float* lnw  = (const float*)d_in[18];
  const float* lnb  = (const float*)d_in[19];

  char* ws = (char*)d_ws;
  const size_t MB = 1ull << 20;
  float*    xx     = (float*)(ws + 0);            // 16MB   (later: yb)
  ushort_t* xxx    = (ushort_t*)(ws + 16 * MB);   // 8MB    (later: Zb)
  ushort_t* WrT    = (ushort_t*)(ws + 24 * MB);
  ushort_t* WkT    = (ushort_t*)(ws + 26 * MB);
  ushort_t* WvT    = (ushort_t*)(ws + 28 * MB);
  ushort_t* WgT    = (ushort_t*)(ws + 30 * MB);
  ushort_t* WoT    = (ushort_t*)(ws + 32 * MB);
  ushort_t* maaW1T = (ushort_t*)(ws + 34 * MB);              // 256x1024
  ushort_t* tdW1T  = (ushort_t*)(ws + 35 * MB);              // 128x1024
  ushort_t* tdW2T  = (ushort_t*)(ws + 35 * MB + 256 * 1024); // 1024x64
  ushort_t* maaW2T = (ushort_t*)(ws + 35 * MB + 512 * 1024); // 1024x160
  ushort_t* t5     = (ushort_t*)(ws + 36 * MB);   // 4096x256 bf16
  ushort_t* t5d    = (ushort_t*)(ws + 38 * MB);   // 4096x128 bf16
  ushort_t* Xm[5];
  for (int f = 0; f < 5; ++f) Xm[f] = (ushort_t*)(ws + 40 * MB + (size_t)f * 8 * MB);
  float* Mbuf = (float*)(ws + 40 * MB);            // 32MB (over Xm[0..3], dead by scan)
  float* Pbuf = (float*)(ws + 72 * MB);            // 512KB (over Xm[4], dead by scan)
  float* rb   = (float*)(ws + 80 * MB);
  float* kb   = (float*)(ws + 96 * MB);
  float* vb   = (float*)(ws + 112 * MB);
  float* gb   = (float*)(ws + 128 * MB);
  float* dec  = (float*)(ws + 144 * MB);
  float* yb   = (float*)(ws + 0);                  // alias xx (dead by then)
  ushort_t* Zb = (ushort_t*)(ws + 16 * MB);        // alias xxx (dead by then)

  // 1) weight transposes/converts
  TArgs ta;
  ta.d[0] = TDesc{Wr,    WrT,    1024, 1024, 1024};
  ta.d[1] = TDesc{Wk,    WkT,    1024, 1024, 1024};
  ta.d[2] = TDesc{Wv,    WvT,    1024, 1024, 1024};
  ta.d[3] = TDesc{Wg,    WgT,    1024, 1024, 1024};
  ta.d[4] = TDesc{Wo,    WoT,    1024, 1024, 1024};
  ta.d[5] = TDesc{maaw1, maaW1T, 1024, 160,  256};
  ta.d[6] = TDesc{tdw1,  tdW1T,  1024, 64,   128};
  ta.d[7] = TDesc{tdw2,  tdW2T,  64,   1024, 1024};
  ta.d[8] = TDesc{maaw2, maaW2T, 160,  1024, 1024};
  transpose_cvt<<<dim3(32, 32, 9), 256, 0, stream>>>(ta);

  // 2) token shift + base mix
  prep_kernel<<<(B_ * T_ * C_) / 1024, 256, 0, stream>>>(x, tmx, xx, xxx);

  // 3) t5 = tanh(xxx @ maa_w1)  (M=4096, N=256pad, K=1024) -> bf16
  gemm_bt<2><<<dim3(32, 2), 256, 0, stream>>>(xxx, C_, maaW1T, C_, t5, 256, C_, nullptr);

  // 4) fused per-f mix: Xm[f] = bf16(x + xx*(tm_f + t5_f @ w2_f))
  MixArgs ma;
  ma.tm[0] = tmw; ma.tm[1] = tmk; ma.tm[2] = tmv; ma.tm[3] = tmr; ma.tm[4] = tmg;
  for (int f = 0; f < 5; ++f) ma.dst[f] = Xm[f];
  fused_mix<<<dim3(64, 8), 256, 0, stream>>>(x, xx, t5, maaW2T, ma);

  // 5) projections r,k,v,g in one batched dispatch (M=4096, N=1024, K=1024)
  PArgs pa;
  pa.d[0] = PDesc{Xm[3], WrT, rb, 0};
  pa.d[1] = PDesc{Xm[1], WkT, kb, 0};
  pa.d[2] = PDesc{Xm[2], WvT, vb, 0};
  pa.d[3] = PDesc{Xm[4], WgT, gb, 1};
  gemm_proj4<<<dim3(32, 8, 4), 256, 0, stream>>>(pa);

  // 6) decay: t5d = tanh(xw @ td_w1); dec = exp(-exp(tdecay + t5d @ td_w2))
  gemm_bt<2><<<dim3(32, 1), 256, 0, stream>>>(Xm[0], C_, tdW1T, C_, t5d, 128, C_, nullptr);
  gemm_bt<4><<<dim3(32, 8), 256, 0, stream>>>(t5d, 128, tdW2T, 64, dec, C_, 64, tdec);

  // 7) chunked scan (u-term folded into pass2; combine is in-place)
  scan_pass1<<<dim3(NCH, B_ * H_), 256, 0, stream>>>(kb, vb, dec, Mbuf, Pbuf);
  scan_combine<<<512, 256, 0, stream>>>(Mbuf, Pbuf);
  scan_pass2<<<dim3(NCH, B_ * H_), 256, 0, stream>>>(rb, kb, vb, dec, u, Mbuf, yb);

  // 8) GroupNorm * gate -> bf16
  gn_kernel<<<B_ * T_ * 4, 256, 0, stream>>>(yb, gb, lnw, lnb, Zb);

  // 9) out = Z @ Wo  (f32)
  gemm_bt<0><<<dim3(32, 8), 256, 0, stream>>>(Zb, C_, WoT, C_, (float*)d_out, C_, C_, nullptr);
}

// Round 3
// 230.781 us; speedup vs baseline: 1.9868x; 1.7380x over previous
//
#include <hip/hip_runtime.h>
#include <hip/hip_bf16.h>
#include <cstdint>
#include <cstddef>

// RWKV6 TimeMix forward, MI355X. B=2 T=2048 C=1024 H=16 N=64.
#define B_ 2
#define T_ 2048
#define C_ 1024
#define H_ 16
#define NCH 32   // chunks per sequence
#define CHL 64   // chunk length

typedef unsigned short ushort_t;
typedef __bf16 bf16x8 __attribute__((ext_vector_type(8)));
typedef float f32x4 __attribute__((ext_vector_type(4)));

__device__ __forceinline__ ushort_t f2bf(float f) {
  union { float f; uint32_t u; } x; x.f = f;
  uint32_t r = x.u + 0x7fffu + ((x.u >> 16) & 1u);
  return (ushort_t)(r >> 16);
}
__device__ __forceinline__ float bf2f(ushort_t h) {
  union { uint32_t u; float f; } x; x.u = (uint32_t)h << 16; return x.f;
}

__device__ __forceinline__ void gload16(const void* g, void* l) {
  __builtin_amdgcn_global_load_lds(
      (const __attribute__((address_space(1))) void*)g,
      (__attribute__((address_space(3))) void*)l, 16, 0, 0);
}

// XOR-swizzled 64x64 bf16 tile helpers (row stride 128B, T2-style swizzle)
__device__ __forceinline__ void stb(ushort_t* tile, int row, int col, ushort_t v) {
  *(ushort_t*)((char*)tile + row * 128 + ((col * 2) ^ ((row & 7) << 4))) = v;
}
__device__ __forceinline__ bf16x8 ldb(const ushort_t* tile, int row, int kbyte) {
  return *(const bf16x8*)((const char*)tile + row * 128 + (kbyte ^ ((row & 7) << 4)));
}

// ---------------- batched transpose + f32->bf16 convert -------------------
struct TDesc { const float* src; ushort_t* dst; int R, Cc, Cpad; };
struct TArgs { TDesc d[9]; };

__global__ __launch_bounds__(256) void transpose_cvt(TArgs args) {
  TDesc D = args.d[blockIdx.z];
  int c0 = blockIdx.x * 32, r0 = blockIdx.y * 32;
  if (c0 >= D.Cpad || r0 >= D.R) return;
  __shared__ float tile[32][33];
  int tx = threadIdx.x & 31, ty = threadIdx.x >> 5;
#pragma unroll
  for (int i = 0; i < 32; i += 8) {
    int r = r0 + ty + i, c = c0 + tx;
    tile[ty + i][tx] = (r < D.R && c < D.Cc) ? D.src[(size_t)r * D.Cc + c] : 0.f;
  }
  __syncthreads();
#pragma unroll
  for (int i = 0; i < 32; i += 8) {
    int c = c0 + ty + i, r = r0 + tx;
    if (c < D.Cpad && r < D.R) D.dst[(size_t)c * D.R + r] = f2bf(tile[tx][ty + i]);
  }
}

// ---------------- prep: xx = shift(x)-x ; xxx = x + xx*tmx (bf16) ---------
__global__ __launch_bounds__(256) void prep_kernel(
    const float* __restrict__ x, const float* __restrict__ tmx,
    float* __restrict__ xx, ushort_t* __restrict__ xxx) {
  size_t idx = ((size_t)blockIdx.x * 256 + threadIdx.x) * 4;
  int tt = (int)((idx >> 10) & (T_ - 1));
  int c = (int)(idx & (C_ - 1));
  float4 xv = *(const float4*)&x[idx];
  float4 xp;
  if (tt == 0) { xp.x = xp.y = xp.z = xp.w = 0.f; }
  else xp = *(const float4*)&x[idx - C_];
  float4 tm = *(const float4*)&tmx[c];
  float4 d;
  d.x = xp.x - xv.x; d.y = xp.y - xv.y; d.z = xp.z - xv.z; d.w = xp.w - xv.w;
  *(float4*)&xx[idx] = d;
  xxx[idx + 0] = f2bf(xv.x + d.x * tm.x);
  xxx[idx + 1] = f2bf(xv.y + d.y * tm.y);
  xxx[idx + 2] = f2bf(xv.z + d.z * tm.z);
  xxx[idx + 3] = f2bf(xv.w + d.w * tm.w);
}

// ---------------- bf16 MFMA GEMM, C = A (MxK) * Bt^T (Bt is NxK) ----------
// EPI: 0 = f32 store, 2 = tanh->bf16, 4 = lambda = exp(aux2+v) ->f32
template <int EPI>
__global__ __launch_bounds__(256) void gemm_bt(
    const ushort_t* __restrict__ A, int lda,
    const ushort_t* __restrict__ Bt, int ldb,
    void* __restrict__ Cp, int ldc, int K,
    const float* __restrict__ aux2) {
  __shared__ ushort_t sA[128 * 32];
  __shared__ ushort_t sB[128 * 32];
  const int t = threadIdx.x;
  const int l = t & 63;
  const int w = t >> 6;
  const int wm = w >> 1, wn = w & 1;
  const int m0 = blockIdx.x * 128, n0 = blockIdx.y * 128;
  const int lr = l & 15;
  const int lk = (l >> 4) * 8;

  f32x4 acc[4][4] = {};

  for (int kt = 0; kt < K; kt += 32) {
    __syncthreads();
#pragma unroll
    for (int it = 0; it < 2; ++it) {
      int cbase = it * 256 + w * 64;
      int ca = cbase + l;
      int row = ca >> 2, kc = ca & 3;
      gload16(A + (size_t)(m0 + row) * lda + kt + kc * 8, (char*)sA + (size_t)cbase * 16);
      gload16(Bt + (size_t)(n0 + row) * ldb + kt + kc * 8, (char*)sB + (size_t)cbase * 16);
    }
    __syncthreads();
    bf16x8 af[4], bfr[4];
#pragma unroll
    for (int mi = 0; mi < 4; ++mi)
      af[mi] = *(const bf16x8*)&sA[(wm * 64 + mi * 16 + lr) * 32 + lk];
#pragma unroll
    for (int ni = 0; ni < 4; ++ni)
      bfr[ni] = *(const bf16x8*)&sB[(wn * 64 + ni * 16 + lr) * 32 + lk];
#pragma unroll
    for (int mi = 0; mi < 4; ++mi)
#pragma unroll
      for (int ni = 0; ni < 4; ++ni)
        acc[mi][ni] = __builtin_amdgcn_mfma_f32_16x16x32_bf16(af[mi], bfr[ni], acc[mi][ni], 0, 0, 0);
  }
#pragma unroll
  for (int mi = 0; mi < 4; ++mi) {
#pragma unroll
    for (int ni = 0; ni < 4; ++ni) {
      int col = n0 + wn * 64 + ni * 16 + lr;
#pragma unroll
      for (int r = 0; r < 4; ++r) {
        int row = m0 + wm * 64 + mi * 16 + (l >> 4) * 4 + r;
        float v = acc[mi][ni][r];
        size_t idx = (size_t)row * ldc + col;
        if constexpr (EPI == 0) {
          ((float*)Cp)[idx] = v;
        } else if constexpr (EPI == 2) {
          ((ushort_t*)Cp)[idx] = f2bf(tanhf(v));
        } else if constexpr (EPI == 4) {
          ((float*)Cp)[idx] = __expf(aux2[col] + v);
        }
      }
    }
  }
}

// ---------------- batched projections r,k,v,g (z-dim selects) --------------
struct PDesc { const ushort_t* A; const ushort_t* Bt; float* C; int epi; };
struct PArgs { PDesc d[4]; };

__global__ __launch_bounds__(256, 3) void gemm_proj4(PArgs args) {
  PDesc D = args.d[blockIdx.z];
  __shared__ ushort_t sA[128 * 32];
  __shared__ ushort_t sB[128 * 32];
  const int t = threadIdx.x;
  const int l = t & 63;
  const int w = t >> 6;
  const int wm = w >> 1, wn = w & 1;
  const int m0 = blockIdx.x * 128, n0 = blockIdx.y * 128;
  const int lr = l & 15;
  const int lk = (l >> 4) * 8;

  f32x4 acc[4][4] = {};

  for (int kt = 0; kt < C_; kt += 32) {
    __syncthreads();
#pragma unroll
    for (int it = 0; it < 2; ++it) {
      int cbase = it * 256 + w * 64;
      int ca = cbase + l;
      int row = ca >> 2, kc = ca & 3;
      gload16(D.A + (size_t)(m0 + row) * C_ + kt + kc * 8, (char*)sA + (size_t)cbase * 16);
      gload16(D.Bt + (size_t)(n0 + row) * C_ + kt + kc * 8, (char*)sB + (size_t)cbase * 16);
    }
    __syncthreads();
    bf16x8 af[4], bfr[4];
#pragma unroll
    for (int mi = 0; mi < 4; ++mi)
      af[mi] = *(const bf16x8*)&sA[(wm * 64 + mi * 16 + lr) * 32 + lk];
#pragma unroll
    for (int ni = 0; ni < 4; ++ni)
      bfr[ni] = *(const bf16x8*)&sB[(wn * 64 + ni * 16 + lr) * 32 + lk];
#pragma unroll
    for (int mi = 0; mi < 4; ++mi)
#pragma unroll
      for (int ni = 0; ni < 4; ++ni)
        acc[mi][ni] = __builtin_amdgcn_mfma_f32_16x16x32_bf16(af[mi], bfr[ni], acc[mi][ni], 0, 0, 0);
  }
  const int epi = D.epi;
#pragma unroll
  for (int mi = 0; mi < 4; ++mi) {
#pragma unroll
    for (int ni = 0; ni < 4; ++ni) {
      int col = n0 + wn * 64 + ni * 16 + lr;
#pragma unroll
      for (int r = 0; r < 4; ++r) {
        int row = m0 + wm * 64 + mi * 16 + (l >> 4) * 4 + r;
        float v = acc[mi][ni][r];
        if (epi) v = v / (1.f + expf(-v));
        D.C[(size_t)row * C_ + col] = v;
      }
    }
  }
}

// ---------------- fused data-dependent mix (5 outputs, x/xx staged once) ---
struct MixArgs { const float* tm[5]; ushort_t* dst[5]; };

__global__ __launch_bounds__(256) void fused_mix(
    const float* __restrict__ x, const float* __restrict__ xx,
    const ushort_t* __restrict__ t5, const ushort_t* __restrict__ w2t,
    MixArgs margs) {
  __shared__ float xs[64 * 128];
  __shared__ float xxs[64 * 128];
  __shared__ ushort_t sA[64 * 32];
  __shared__ ushort_t sB[128 * 32];
  const int t = threadIdx.x;
  const int l = t & 63;
  const int w = t >> 6;
  const int wm = w >> 1, wn = w & 1;
  const int m0 = blockIdx.x * 64, n0 = blockIdx.y * 128;
  const int lr = l & 15;
  const int lk = (l >> 4) * 8;

#pragma unroll
  for (int it = 0; it < 8; ++it) {
    int row = it * 8 + (t >> 5);
    int c16 = t & 31;
    gload16(x + (size_t)(m0 + row) * C_ + n0 + c16 * 4, (char*)xs + row * 512 + c16 * 16);
    gload16(xx + (size_t)(m0 + row) * C_ + n0 + c16 * 4, (char*)xxs + row * 512 + c16 * 16);
  }

  for (int f = 0; f < 5; ++f) {
    __syncthreads();
    {
      int row = t >> 2, c8 = t & 3;
      gload16(t5 + (size_t)(m0 + row) * 256 + f * 32 + c8 * 8, (char*)sA + t * 16);
    }
#pragma unroll
    for (int it = 0; it < 2; ++it) {
      int row = it * 64 + (t >> 2), c8 = t & 3;
      gload16(w2t + (size_t)(n0 + row) * 160 + f * 32 + c8 * 8,
              (char*)sB + it * 4096 + t * 16);
    }
    __syncthreads();
    bf16x8 af[2], bfr[4];
#pragma unroll
    for (int mi = 0; mi < 2; ++mi)
      af[mi] = *(const bf16x8*)&sA[(wm * 32 + mi * 16 + lr) * 32 + lk];
#pragma unroll
    for (int ni = 0; ni < 4; ++ni)
      bfr[ni] = *(const bf16x8*)&sB[(wn * 64 + ni * 16 + lr) * 32 + lk];
    f32x4 acc[2][4] = {};
#pragma unroll
    for (int mi = 0; mi < 2; ++mi)
#pragma unroll
      for (int ni = 0; ni < 4; ++ni)
        acc[mi][ni] = __builtin_amdgcn_mfma_f32_16x16x32_bf16(af[mi], bfr[ni], acc[mi][ni], 0, 0, 0);
    const float* tmf = margs.tm[f];
    ushort_t* dst = margs.dst[f];
#pragma unroll
    for (int mi = 0; mi < 2; ++mi) {
#pragma unroll
      for (int ni = 0; ni < 4; ++ni) {
        int cl = wn * 64 + ni * 16 + lr;
        int col = n0 + cl;
        float tmv = tmf[col];
#pragma unroll
        for (int r = 0; r < 4; ++r) {
          int rl = wm * 32 + mi * 16 + (l >> 4) * 4 + r;
          int row = m0 + rl;
          float xv = xs[rl * 128 + cl];
          float xxv = xxs[rl * 128 + cl];
          dst[(size_t)row * C_ + col] = f2bf(xv + xxv * (tmv + acc[mi][ni][r]));
        }
      }
    }
  }
}

// ---------------- K1: chunk-local MFMA scan --------------------------------
// Per (chunk c, bh): lambda cumsums -> rA, kA, kAL(hi/lo), V(hi/lo) tiles;
// P = tril_strict(rA@kA^T) + diag(ruk); y_intra = P@V; Mt = V^T@kAL; aL.
__global__ __launch_bounds__(256) void chunk_local(
    const float* __restrict__ rx, const float* __restrict__ kx,
    const float* __restrict__ vx, const float* __restrict__ lamx,
    const float* __restrict__ u, float* __restrict__ Mt,
    float* __restrict__ aLg, ushort_t* __restrict__ rAg,
    float* __restrict__ yo) {
  int c = blockIdx.x, bh = blockIdx.y;
  int b = bh >> 4, h = bh & 15;
  __shared__ ushort_t sRA[64 * 64], sKA[64 * 64], sKh[64 * 64], sKl[64 * 64],
                      sVh[64 * 64], sVl[64 * 64], sP[64 * 64];
  __shared__ float qsum[4][64];
  __shared__ float ruk[64];
  const int tid = threadIdx.x;
  const int i = tid & 63;       // channel lane
  const int q = tid >> 6;       // t-quarter
  size_t base = ((size_t)b * T_ + (size_t)c * CHL) * C_ + h * 64;
  size_t cb = ((size_t)c * 32 + bh);

  // ---- phase A: lambda cumsum + tile builds ----
  float lam[16];
  float run = 0.f;
#pragma unroll
  for (int s = 0; s < 16; ++s) {
    lam[s] = lamx[base + (size_t)(q * 16 + s) * C_ + i];
    run += lam[s];
  }
  qsum[q][i] = run;
  __syncthreads();
  float pre = 0.f, ct = 0.f;
#pragma unroll
  for (int qq = 0; qq < 4; ++qq) {
    float vq = qsum[qq][i];
    ct += vq;
    if (qq < q) pre += vq;
  }
  float uu = u[h * 64 + i];
  float ci = pre;
#pragma unroll
  for (int s = 0; s < 16; ++s) {
    int t = q * 16 + s;
    ci += lam[s];
    float cl = ci - lam[s];
    size_t o = base + (size_t)t * C_ + i;
    float rv = rx[o], kv = kx[o], vv = vx[o];
    ushort_t ra = f2bf(rv * __expf(-cl));
    stb(sRA, t, i, ra);
    rAg[cb * 4096 + t * 64 + i] = ra;
    stb(sKA, t, i, f2bf(kv * __expf(ci)));
    float kal = kv * __expf(ci - ct);
    ushort_t khv = f2bf(kal);
    stb(sKh, i, t, khv);
    stb(sKl, i, t, f2bf(kal - bf2f(khv)));
    ushort_t vhv = f2bf(vv);
    stb(sVh, i, t, vhv);
    stb(sVl, i, t, f2bf(vv - bf2f(vhv)));
    float rr = rv * uu * kv;
#pragma unroll
    for (int m = 32; m; m >>= 1) rr += __shfl_xor(rr, m);
    if (i == 0) ruk[t] = rr;
  }
  if (q == 0) aLg[cb * 64 + i] = __expf(-ct);
  __syncthreads();

  const int l = tid & 63, w = tid >> 6;
  const int wm = w >> 1, wn = w & 1;
  const int lr = l & 15, hi4 = l >> 4;

  // ---- phase B: P = rA @ kA^T, mask, store bf16 ----
  {
    f32x4 accP[2][2] = {};
#pragma unroll
    for (int kk = 0; kk < 2; ++kk) {
      bf16x8 af[2], bf_[2];
#pragma unroll
      for (int mi = 0; mi < 2; ++mi) af[mi] = ldb(sRA, wm * 32 + mi * 16 + lr, kk * 64 + hi4 * 16);
#pragma unroll
      for (int ni = 0; ni < 2; ++ni) bf_[ni] = ldb(sKA, wn * 32 + ni * 16 + lr, kk * 64 + hi4 * 16);
#pragma unroll
      for (int mi = 0; mi < 2; ++mi)
#pragma unroll
        for (int ni = 0; ni < 2; ++ni)
          accP[mi][ni] = __builtin_amdgcn_mfma_f32_16x16x32_bf16(af[mi], bf_[ni], accP[mi][ni], 0, 0, 0);
    }
#pragma unroll
    for (int mi = 0; mi < 2; ++mi)
#pragma unroll
      for (int ni = 0; ni < 2; ++ni)
#pragma unroll
        for (int r = 0; r < 4; ++r) {
          int tl = wm * 32 + mi * 16 + hi4 * 4 + r, sl = wn * 32 + ni * 16 + lr;
          float v = accP[mi][ni][r];
          v = sl < tl ? v : (sl == tl ? ruk[tl] : 0.f);
          stb(sP, tl, sl, f2bf(v));
        }
  }
  __syncthreads();

  // ---- phase C: y_intra = P@(Vh+Vl);  Mt = (Vh+Vl)^T @ (kh+kl) ----
  f32x4 accY[2][2] = {}, accM[2][2] = {};
#pragma unroll
  for (int kk = 0; kk < 2; ++kk) {
    bf16x8 pa[2], vhA[2], vlA[2], vhB[2], vlB[2], khB[2], klB[2];
#pragma unroll
    for (int mi = 0; mi < 2; ++mi) {
      int rw = wm * 32 + mi * 16 + lr;
      pa[mi] = ldb(sP, rw, kk * 64 + hi4 * 16);
      vhA[mi] = ldb(sVh, rw, kk * 64 + hi4 * 16);
      vlA[mi] = ldb(sVl, rw, kk * 64 + hi4 * 16);
    }
#pragma unroll
    for (int ni = 0; ni < 2; ++ni) {
      int rw = wn * 32 + ni * 16 + lr;
      vhB[ni] = ldb(sVh, rw, kk * 64 + hi4 * 16);
      vlB[ni] = ldb(sVl, rw, kk * 64 + hi4 * 16);
      khB[ni] = ldb(sKh, rw, kk * 64 + hi4 * 16);
      klB[ni] = ldb(sKl, rw, kk * 64 + hi4 * 16);
    }
#pragma unroll
    for (int mi = 0; mi < 2; ++mi)
#pragma unroll
      for (int ni = 0; ni < 2; ++ni) {
        accY[mi][ni] = __builtin_amdgcn_mfma_f32_16x16x32_bf16(pa[mi], vhB[ni], accY[mi][ni], 0, 0, 0);
        accY[mi][ni] = __builtin_amdgcn_mfma_f32_16x16x32_bf16(pa[mi], vlB[ni], accY[mi][ni], 0, 0, 0);
        accM[mi][ni] = __builtin_amdgcn_mfma_f32_16x16x32_bf16(vhA[mi], khB[ni], accM[mi][ni], 0, 0, 0);
        accM[mi][ni] = __builtin_amdgcn_mfma_f32_16x16x32_bf16(vhA[mi], klB[ni], accM[mi][ni], 0, 0, 0);
        accM[mi][ni] = __builtin_amdgcn_mfma_f32_16x16x32_bf16(vlA[mi], khB[ni], accM[mi][ni], 0, 0, 0);
      }
  }
#pragma unroll
  for (int mi = 0; mi < 2; ++mi)
#pragma unroll
    for (int ni = 0; ni < 2; ++ni)
#pragma unroll
      for (int r = 0; r < 4; ++r) {
        int rw = wm * 32 + mi * 16 + hi4 * 4 + r;
        int cw = wn * 32 + ni * 16 + lr;
        yo[base + (size_t)rw * C_ + cw] = accY[mi][ni][r];     // y_intra[t][j]
        Mt[cb * 4096 + rw * 64 + cw] = accM[mi][ni][r];        // Mt[j][i]
      }
}

// ---------------- K2: sequential chunk combine (S0 in bf16 hi/lo) ----------
__global__ __launch_bounds__(256) void combine2(
    const float* __restrict__ Mt, const float* __restrict__ aLg,
    ushort_t* __restrict__ S0h, ushort_t* __restrict__ S0l) {
  int bh = blockIdx.x >> 4;
  int ij = (blockIdx.x & 15) * 256 + threadIdx.x;   // [j][i] linear
  int i = ij & 63;
  float s = 0.f;
  for (int c = 0; c < NCH; ++c) {
    size_t o = ((size_t)c * 32 + bh) * 4096 + ij;
    float m = Mt[o];
    float p = aLg[((size_t)c * 32 + bh) * 64 + i];
    ushort_t hi = f2bf(s);
    S0h[o] = hi;
    S0l[o] = f2bf(s - bf2f(hi));
    s = p * s + m;
  }
}

// ---------------- K3: y = y_intra + rA@S0, GroupNorm, *g -> bf16 Z ---------
__global__ __launch_bounds__(256) void inter_gn(
    const ushort_t* __restrict__ rAg, const ushort_t* __restrict__ S0h,
    const ushort_t* __restrict__ S0l, const float* __restrict__ yin,
    const float* __restrict__ gx, const float* __restrict__ lnw,
    const float* __restrict__ lnb, ushort_t* __restrict__ Z) {
  int c = blockIdx.x, bh = blockIdx.y;
  int b = bh >> 4, h = bh & 15;
  __shared__ ushort_t sRA[64 * 64], sSh[64 * 64], sSl[64 * 64];
  __shared__ float st[64][2][2];
  const int tid = threadIdx.x;
  size_t cb = ((size_t)c * 32 + bh) * 4096;
  // swizzled LDS copies
#pragma unroll
  for (int it = 0; it < 2; ++it) {
    int lb = tid * 32 + it * 16;
    int row = lb >> 7, wi = lb & 127;
    int so = row * 128 + (wi ^ ((row & 7) << 4));
    *(uint4*)((char*)sRA + so) = *(const uint4*)((const char*)(rAg + cb) + lb);
    *(uint4*)((char*)sSh + so) = *(const uint4*)((const char*)(S0h + cb) + lb);
    *(uint4*)((char*)sSl + so) = *(const uint4*)((const char*)(S0l + cb) + lb);
  }
  const int l = tid & 63, w = tid >> 6;
  const int wm = w >> 1, wn = w & 1;
  const int lr = l & 15, hi4 = l >> 4;
  size_t base = ((size_t)b * T_ + (size_t)c * CHL) * C_ + h * 64;

  f32x4 acc[2][2];
#pragma unroll
  for (int mi = 0; mi < 2; ++mi)
#pragma unroll
    for (int ni = 0; ni < 2; ++ni)
#pragma unroll
      for (int r = 0; r < 4; ++r)
        acc[mi][ni][r] = yin[base + (size_t)(wm * 32 + mi * 16 + hi4 * 4 + r) * C_ +
                             wn * 32 + ni * 16 + lr];
  __syncthreads();
#pragma unroll
  for (int kk = 0; kk < 2; ++kk) {
    bf16x8 af[2], bh_[2], bl_[2];
#pragma unroll
    for (int mi = 0; mi < 2; ++mi) af[mi] = ldb(sRA, wm * 32 + mi * 16 + lr, kk * 64 + hi4 * 16);
#pragma unroll
    for (int ni = 0; ni < 2; ++ni) {
      bh_[ni] = ldb(sSh, wn * 32 + ni * 16 + lr, kk * 64 + hi4 * 16);
      bl_[ni] = ldb(sSl, wn * 32 + ni * 16 + lr, kk * 64 + hi4 * 16);
    }
#pragma unroll
    for (int mi = 0; mi < 2; ++mi)
#pragma unroll
      for (int ni = 0; ni < 2; ++ni) {
        acc[mi][ni] = __builtin_amdgcn_mfma_f32_16x16x32_bf16(af[mi], bh_[ni], acc[mi][ni], 0, 0, 0);
        acc[mi][ni] = __builtin_amdgcn_mfma_f32_16x16x32_bf16(af[mi], bl_[ni], acc[mi][ni], 0, 0, 0);
      }
  }
  // GroupNorm stats over the 64 cols of this head
#pragma unroll
  for (int mi = 0; mi < 2; ++mi)
#pragma unroll
    for (int r = 0; r < 4; ++r) {
      int row = wm * 32 + mi * 16 + hi4 * 4 + r;
      float s1 = acc[mi][0][r] + acc[mi][1][r];
      float s2 = acc[mi][0][r] * acc[mi][0][r] + acc[mi][1][r] * acc[mi][1][r];
#pragma unroll
      for (int m = 1; m < 16; m <<= 1) { s1 += __shfl_xor(s1, m); s2 += __shfl_xor(s2, m); }
      if (lr == 0) { st[row][wn][0] = s1; st[row][wn][1] = s2; }
    }
  __syncthreads();
#pragma unroll
  for (int mi = 0; mi < 2; ++mi)
#pragma unroll
    for (int ni = 0; ni < 2; ++ni)
#pragma unroll
      for (int r = 0; r < 4; ++r) {
        int row = wm * 32 + mi * 16 + hi4 * 4 + r;
        int jl = wn * 32 + ni * 16 + lr;
        float S1 = st[row][0][0] + st[row][1][0];
        float S2 = st[row][0][1] + st[row][1][1];
        float mu = S1 * (1.f / 64.f);
        float var = S2 * (1.f / 64.f) - mu * mu;
        float rs = rsqrtf(var + 6.4e-4f);          // EPS = 1e-5 * 64
        int col = h * 64 + jl;
        size_t o = base + (size_t)row * C_ + jl;
        float yn = (acc[mi][ni][r] - mu) * rs * lnw[col] + lnb[col];
        Z[o] = f2bf(yn * gx[o]);
      }
}

// ===========================================================================
extern "C" void kernel_launch(void* const* d_in, const int* in_sizes, int n_in,
                              void* d_out, int out_size, void* d_ws, size_t ws_size,
                              hipStream_t stream) {
  const float* x    = (const float*)d_in[0];
  const float* tmx  = (const float*)d_in[1];
  const float* tmw  = (const float*)d_in[2];
  const float* tmk  = (const float*)d_in[3];
  const float* tmv  = (const float*)d_in[4];
  const float* tmr  = (const float*)d_in[5];
  const float* tmg  = (const float*)d_in[6];
  const float* maaw1 = (const float*)d_in[7];
  const float* maaw2 = (const float*)d_in[8];
  const float* tdec = (const float*)d_in[9];
  const float* tdw1 = (const float*)d_in[10];
  const float* tdw2 = (const float*)d_in[11];
  const float* u    = (const float*)d_in[12];
  const float* Wr   = (const float*)d_in[13];
  const float* Wk   = (const float*)d_in[14];
  const float* Wv   = (const float*)d_in[15];
  const float* Wg   = (const float*)d_in[16];
  const float* Wo   = (const float*)d_in[17];
  const float* lnw  = (const float*)d_in[18];
  const float* lnb  = (const float*)d_in[19];

  char* ws = (char*)d_ws;
  const size_t MB = 1ull << 20;
  float*    xx     = (float*)(ws + 0);            // 16MB (later: yb)
  ushort_t* xxx    = (ushort_t*)(ws + 16 * MB);   // 8MB  (later: Zb)
  ushort_t* WrT    = (ushort_t*)(ws + 24 * MB);
  ushort_t* WkT    = (ushort_t*)(ws + 26 * MB);
  ushort_t* WvT    = (ushort_t*)(ws + 28 * MB);
  ushort_t* WgT    = (ushort_t*)(ws + 30 * MB);
  ushort_t* WoT    = (ushort_t*)(ws + 32 * MB);
  ushort_t* maaW1T = (ushort_t*)(ws + 34 * MB);              // 256x1024
  ushort_t* tdW1T  = (ushort_t*)(ws + 35 * MB);              // 128x1024
  ushort_t* tdW2T  = (ushort_t*)(ws + 35 * MB + 256 * 1024); // 1024x64
  ushort_t* maaW2T = (ushort_t*)(ws + 35 * MB + 512 * 1024); // 1024x160
  ushort_t* t5     = (ushort_t*)(ws + 36 * MB);   // 4096x256 bf16
  ushort_t* t5d    = (ushort_t*)(ws + 38 * MB);   // 4096x128 bf16
  ushort_t* Xm[5];
  for (int f = 0; f < 5; ++f) Xm[f] = (ushort_t*)(ws + 40 * MB + (size_t)f * 8 * MB);
  float*    Mtb = (float*)(ws + 40 * MB);          // 16MB  (over Xm[0..1], dead)
  ushort_t* S0h = (ushort_t*)(ws + 56 * MB);       // 8MB   (over Xm[2])
  ushort_t* S0l = (ushort_t*)(ws + 64 * MB);       // 8MB   (over Xm[3])
  ushort_t* rAg = (ushort_t*)(ws + 72 * MB);       // 8MB   (over Xm[4])
  float* rb   = (float*)(ws + 80 * MB);
  float* kb   = (float*)(ws + 96 * MB);
  float* vb   = (float*)(ws + 112 * MB);
  float* gb   = (float*)(ws + 128 * MB);
  float* lam  = (float*)(ws + 144 * MB);
  float* aLg  = (float*)(ws + 160 * MB);           // 256KB
  float* yb   = (float*)(ws + 0);                  // alias xx (dead by then)
  ushort_t* Zb = (ushort_t*)(ws + 16 * MB);        // alias xxx (dead by then)

  // 1) weight transposes/converts
  TArgs ta;
  ta.d[0] = TDesc{Wr,    WrT,    1024, 1024, 1024};
  ta.d[1] = TDesc{Wk,    WkT,    1024, 1024, 1024};
  ta.d[2] = TDesc{Wv,    WvT,    1024, 1024, 1024};
  ta.d[3] = TDesc{Wg,    WgT,    1024, 1024, 1024};
  ta.d[4] = TDesc{Wo,    WoT,    1024, 1024, 1024};
  ta.d[5] = TDesc{maaw1, maaW1T, 1024, 160,  256};
  ta.d[6] = TDesc{tdw1,  tdW1T,  1024, 64,   128};
  ta.d[7] = TDesc{tdw2,  tdW2T,  64,   1024, 1024};
  ta.d[8] = TDesc{maaw2, maaW2T, 160,  1024, 1024};
  transpose_cvt<<<dim3(32, 32, 9), 256, 0, stream>>>(ta);

  // 2) token shift + base mix
  prep_kernel<<<(B_ * T_ * C_) / 1024, 256, 0, stream>>>(x, tmx, xx, xxx);

  // 3) t5 = tanh(xxx @ maa_w1)
  gemm_bt<2><<<dim3(32, 2), 256, 0, stream>>>(xxx, C_, maaW1T, C_, t5, 256, C_, nullptr);

  // 4) fused per-f mix
  MixArgs ma;
  ma.tm[0] = tmw; ma.tm[1] = tmk; ma.tm[2] = tmv; ma.tm[3] = tmr; ma.tm[4] = tmg;
  for (int f = 0; f < 5; ++f) ma.dst[f] = Xm[f];
  fused_mix<<<dim3(64, 8), 256, 0, stream>>>(x, xx, t5, maaW2T, ma);

  // 5) projections r,k,v,g
  PArgs pa;
  pa.d[0] = PDesc{Xm[3], WrT, rb, 0};
  pa.d[1] = PDesc{Xm[1], WkT, kb, 0};
  pa.d[2] = PDesc{Xm[2], WvT, vb, 0};
  pa.d[3] = PDesc{Xm[4], WgT, gb, 1};
  gemm_proj4<<<dim3(32, 8, 4), 256, 0, stream>>>(pa);

  // 6) decay: t5d = tanh(xw @ td_w1); lam = exp(tdecay + t5d @ td_w2)
  gemm_bt<2><<<dim3(32, 1), 256, 0, stream>>>(Xm[0], C_, tdW1T, C_, t5d, 128, C_, nullptr);
  gemm_bt<4><<<dim3(32, 8), 256, 0, stream>>>(t5d, 128, tdW2T, 64, lam, C_, 64, tdec);

  // 7) MFMA chunked scan
  chunk_local<<<dim3(NCH, B_ * H_), 256, 0, stream>>>(rb, kb, vb, lam, u, Mtb, aLg, rAg, yb);
  combine2<<<512, 256, 0, stream>>>(Mtb, aLg, S0h, S0l);
  inter_gn<<<dim3(NCH, B_ * H_), 256, 0, stream>>>(rAg, S0h, S0l, yb, gb, lnw, lnb, Zb);

  // 8) out = Z @ Wo
  gemm_bt<0><<<dim3(32, 8), 256, 0, stream>>>(Zb, C_, WoT, C_, (float*)d_out, C_, C_, nullptr);
}

// Round 4
// 210.944 us; speedup vs baseline: 2.1736x; 1.0940x over previous
//
#include <hip/hip_runtime.h>
#include <hip/hip_bf16.h>
#include <cstdint>
#include <cstddef>

// RWKV6 TimeMix forward, MI355X. B=2 T=2048 C=1024 H=16 N=64.
#define B_ 2
#define T_ 2048
#define C_ 1024
#define H_ 16
#define NCH 32   // chunks per sequence
#define CHL 64   // chunk length

typedef unsigned short ushort_t;
typedef __bf16 bf16x8 __attribute__((ext_vector_type(8)));
typedef float f32x4 __attribute__((ext_vector_type(4)));

__device__ __forceinline__ ushort_t f2bf(float f) {
  union { float f; uint32_t u; } x; x.f = f;
  uint32_t r = x.u + 0x7fffu + ((x.u >> 16) & 1u);
  return (ushort_t)(r >> 16);
}
__device__ __forceinline__ float bf2f(ushort_t h) {
  union { uint32_t u; float f; } x; x.u = (uint32_t)h << 16; return x.f;
}

__device__ __forceinline__ void gload16(const void* g, void* l) {
  __builtin_amdgcn_global_load_lds(
      (const __attribute__((address_space(1))) void*)g,
      (__attribute__((address_space(3))) void*)l, 16, 0, 0);
}

#define FENCE() asm volatile("" ::: "memory")
#define BAR() do { FENCE(); __builtin_amdgcn_s_barrier(); FENCE(); } while (0)

// XOR-swizzled 64x64 bf16 tile helpers (row stride 128B, T2-style swizzle)
__device__ __forceinline__ void stb(ushort_t* tile, int row, int col, ushort_t v) {
  *(ushort_t*)((char*)tile + row * 128 + ((col * 2) ^ ((row & 7) << 4))) = v;
}
__device__ __forceinline__ bf16x8 ldb(const ushort_t* tile, int row, int kbyte) {
  return *(const bf16x8*)((const char*)tile + row * 128 + (kbyte ^ ((row & 7) << 4)));
}

// ---------------- batched transpose + f32->bf16 convert -------------------
struct TDesc { const float* src; ushort_t* dst; int R, Cc, Cpad; };
struct TArgs { TDesc d[9]; };

__global__ __launch_bounds__(256) void transpose_cvt(TArgs args) {
  TDesc D = args.d[blockIdx.z];
  int c0 = blockIdx.x * 32, r0 = blockIdx.y * 32;
  if (c0 >= D.Cpad || r0 >= D.R) return;
  __shared__ float tile[32][33];
  int tx = threadIdx.x & 31, ty = threadIdx.x >> 5;
#pragma unroll
  for (int i = 0; i < 32; i += 8) {
    int r = r0 + ty + i, c = c0 + tx;
    tile[ty + i][tx] = (r < D.R && c < D.Cc) ? D.src[(size_t)r * D.Cc + c] : 0.f;
  }
  __syncthreads();
#pragma unroll
  for (int i = 0; i < 32; i += 8) {
    int c = c0 + ty + i, r = r0 + tx;
    if (c < D.Cpad && r < D.R) D.dst[(size_t)c * D.R + r] = f2bf(tile[tx][ty + i]);
  }
}

// ---------------- prep: xx = shift(x)-x ; xxx = x + xx*tmx (bf16) ---------
__global__ __launch_bounds__(256) void prep_kernel(
    const float* __restrict__ x, const float* __restrict__ tmx,
    float* __restrict__ xx, ushort_t* __restrict__ xxx) {
  size_t idx = ((size_t)blockIdx.x * 256 + threadIdx.x) * 4;
  int tt = (int)((idx >> 10) & (T_ - 1));
  int c = (int)(idx & (C_ - 1));
  float4 xv = *(const float4*)&x[idx];
  float4 xp;
  if (tt == 0) { xp.x = xp.y = xp.z = xp.w = 0.f; }
  else xp = *(const float4*)&x[idx - C_];
  float4 tm = *(const float4*)&tmx[c];
  float4 d;
  d.x = xp.x - xv.x; d.y = xp.y - xv.y; d.z = xp.z - xv.z; d.w = xp.w - xv.w;
  *(float4*)&xx[idx] = d;
  xxx[idx + 0] = f2bf(xv.x + d.x * tm.x);
  xxx[idx + 1] = f2bf(xv.y + d.y * tm.y);
  xxx[idx + 2] = f2bf(xv.z + d.z * tm.z);
  xxx[idx + 3] = f2bf(xv.w + d.w * tm.w);
}

// ---------------- bf16 MFMA GEMM 128x128, C = A * Bt^T ---------------------
// EPI: 0 = f32 store, 4 = lambda = exp(aux2+v) -> f32
template <int EPI>
__global__ __launch_bounds__(256) void gemm_bt(
    const ushort_t* __restrict__ A, int lda,
    const ushort_t* __restrict__ Bt, int ldb,
    void* __restrict__ Cp, int ldc, int K,
    const float* __restrict__ aux2) {
  __shared__ ushort_t sA[128 * 32];
  __shared__ ushort_t sB[128 * 32];
  const int t = threadIdx.x;
  const int l = t & 63;
  const int w = t >> 6;
  const int wm = w >> 1, wn = w & 1;
  const int m0 = blockIdx.x * 128, n0 = blockIdx.y * 128;
  const int lr = l & 15;
  const int lk = (l >> 4) * 8;

  f32x4 acc[4][4] = {};

  for (int kt = 0; kt < K; kt += 32) {
    __syncthreads();
#pragma unroll
    for (int it = 0; it < 2; ++it) {
      int cbase = it * 256 + w * 64;
      int ca = cbase + l;
      int row = ca >> 2, kc = ca & 3;
      gload16(A + (size_t)(m0 + row) * lda + kt + kc * 8, (char*)sA + (size_t)cbase * 16);
      gload16(Bt + (size_t)(n0 + row) * ldb + kt + kc * 8, (char*)sB + (size_t)cbase * 16);
    }
    __syncthreads();
    bf16x8 af[4], bfr[4];
#pragma unroll
    for (int mi = 0; mi < 4; ++mi)
      af[mi] = *(const bf16x8*)&sA[(wm * 64 + mi * 16 + lr) * 32 + lk];
#pragma unroll
    for (int ni = 0; ni < 4; ++ni)
      bfr[ni] = *(const bf16x8*)&sB[(wn * 64 + ni * 16 + lr) * 32 + lk];
#pragma unroll
    for (int mi = 0; mi < 4; ++mi)
#pragma unroll
      for (int ni = 0; ni < 4; ++ni)
        acc[mi][ni] = __builtin_amdgcn_mfma_f32_16x16x32_bf16(af[mi], bfr[ni], acc[mi][ni], 0, 0, 0);
  }
#pragma unroll
  for (int mi = 0; mi < 4; ++mi) {
#pragma unroll
    for (int ni = 0; ni < 4; ++ni) {
      int col = n0 + wn * 64 + ni * 16 + lr;
#pragma unroll
      for (int r = 0; r < 4; ++r) {
        int row = m0 + wm * 64 + mi * 16 + (l >> 4) * 4 + r;
        float v = acc[mi][ni][r];
        size_t idx = (size_t)row * ldc + col;
        if constexpr (EPI == 0) {
          ((float*)Cp)[idx] = v;
        } else if constexpr (EPI == 4) {
          ((float*)Cp)[idx] = __expf(aux2[col] + v);
        }
      }
    }
  }
}

// ---------------- narrow GEMM 64x128 tile, tanh->bf16 ----------------------
__global__ __launch_bounds__(256) void gemm_bt64(
    const ushort_t* __restrict__ A, int lda,
    const ushort_t* __restrict__ Bt, int ldb,
    ushort_t* __restrict__ Cp, int ldc, int K) {
  __shared__ ushort_t sA[64 * 32];
  __shared__ ushort_t sB[128 * 32];
  const int t = threadIdx.x;
  const int l = t & 63;
  const int w = t >> 6;          // wave -> 32-col quarter of N
  const int m0 = blockIdx.x * 64, n0 = blockIdx.y * 128;
  const int lr = l & 15, lk = (l >> 4) * 8;

  f32x4 acc[4][2] = {};
  for (int kt = 0; kt < K; kt += 32) {
    __syncthreads();
    {
      int row = t >> 2, kc = t & 3;
      gload16(A + (size_t)(m0 + row) * lda + kt + kc * 8, (char*)sA + w * 1024);
    }
#pragma unroll
    for (int it = 0; it < 2; ++it) {
      int ca = it * 256 + t;
      int row = ca >> 2, kc = ca & 3;
      gload16(Bt + (size_t)(n0 + row) * ldb + kt + kc * 8,
              (char*)sB + it * 4096 + w * 1024);
    }
    __syncthreads();
    bf16x8 af[4], bfr[2];
#pragma unroll
    for (int mi = 0; mi < 4; ++mi)
      af[mi] = *(const bf16x8*)&sA[(mi * 16 + lr) * 32 + lk];
#pragma unroll
    for (int ni = 0; ni < 2; ++ni)
      bfr[ni] = *(const bf16x8*)&sB[(w * 32 + ni * 16 + lr) * 32 + lk];
#pragma unroll
    for (int mi = 0; mi < 4; ++mi)
#pragma unroll
      for (int ni = 0; ni < 2; ++ni)
        acc[mi][ni] = __builtin_amdgcn_mfma_f32_16x16x32_bf16(af[mi], bfr[ni], acc[mi][ni], 0, 0, 0);
  }
#pragma unroll
  for (int mi = 0; mi < 4; ++mi)
#pragma unroll
    for (int ni = 0; ni < 2; ++ni) {
      int col = n0 + w * 32 + ni * 16 + lr;
#pragma unroll
      for (int r = 0; r < 4; ++r) {
        int row = m0 + mi * 16 + (l >> 4) * 4 + r;
        Cp[(size_t)row * ldc + col] = f2bf(tanhf(acc[mi][ni][r]));
      }
    }
}

// ---------------- 256x256 pipelined projections r,k,v,g --------------------
// 512 thr, 8 waves (2M x 4N), BK=64, 128KiB LDS double-buffer, counted vmcnt,
// T2 swizzle via pre-swizzled global source (linear LDS dest) + swizzled read.
struct PDesc { const ushort_t* A; const ushort_t* Bt; float* C; int epi; };
struct PArgs { PDesc d[4]; };

__device__ __forceinline__ bf16x8 ldsw(const ushort_t* t_, int row, int slot) {
  return *(const bf16x8*)((const char*)t_ + row * 128 + (((slot ^ (row & 7)) << 4)));
}

__global__ __launch_bounds__(512, 2) void gemm_proj256(PArgs args) {
  PDesc D = args.d[blockIdx.z];
  __shared__ ushort_t sA0[256 * 64], sB0[256 * 64], sA1[256 * 64], sB1[256 * 64];
  const int tid = threadIdx.x;
  const int w = tid >> 6, l = tid & 63;
  const int wm = w >> 2, wn = w & 3;
  const int lr = l & 15, hi4 = l >> 4;
  const int m0 = blockIdx.x * 256, n0 = blockIdx.y * 256;

  const int srow = tid >> 3;                        // 0..63 (row within 64-row quarter)
  const int scol = ((tid & 7) ^ (srow & 7)) << 3;   // inverse-swizzled k offset (elems)
  const ushort_t* Ag = D.A + (size_t)(m0 + srow) * C_ + scol;
  const ushort_t* Bg = D.Bt + (size_t)(n0 + srow) * C_ + scol;
  const int wb = w * 1024;                          // wave byte base inside 8KB quarter

  f32x4 acc[8][4] = {};

#define STAGE256(sa, sb, kt)                                        \
  do {                                                              \
    const ushort_t* ap_ = Ag + (kt);                                \
    const ushort_t* bp_ = Bg + (kt);                                \
    gload16(ap_,            (char*)(sa) + 0 * 8192 + wb);           \
    gload16(ap_ +  64 * C_, (char*)(sa) + 1 * 8192 + wb);           \
    gload16(ap_ + 128 * C_, (char*)(sa) + 2 * 8192 + wb);           \
    gload16(ap_ + 192 * C_, (char*)(sa) + 3 * 8192 + wb);           \
    gload16(bp_,            (char*)(sb) + 0 * 8192 + wb);           \
    gload16(bp_ +  64 * C_, (char*)(sb) + 1 * 8192 + wb);           \
    gload16(bp_ + 128 * C_, (char*)(sb) + 2 * 8192 + wb);           \
    gload16(bp_ + 192 * C_, (char*)(sb) + 3 * 8192 + wb);           \
  } while (0)

#define KSTEP256(CA, CB, t)                                                  \
  do {                                                                       \
    if ((t) < 15) asm volatile("s_waitcnt vmcnt(8)" ::: "memory");           \
    else          asm volatile("s_waitcnt vmcnt(0)" ::: "memory");           \
    BAR();                                                                   \
    _Pragma("unroll")                                                        \
    for (int kk = 0; kk < 2; ++kk) {                                         \
      bf16x8 bfrag[4];                                                       \
      _Pragma("unroll")                                                      \
      for (int ni = 0; ni < 4; ++ni)                                         \
        bfrag[ni] = ldsw(CB, wn * 64 + ni * 16 + lr, kk * 4 + hi4);          \
      __builtin_amdgcn_s_setprio(1);                                         \
      _Pragma("unroll")                                                      \
      for (int mi = 0; mi < 8; ++mi) {                                       \
        bf16x8 af = ldsw(CA, wm * 128 + mi * 16 + lr, kk * 4 + hi4);         \
        _Pragma("unroll")                                                    \
        for (int ni = 0; ni < 4; ++ni)                                       \
          acc[mi][ni] = __builtin_amdgcn_mfma_f32_16x16x32_bf16(             \
              af, bfrag[ni], acc[mi][ni], 0, 0, 0);                          \
      }                                                                      \
      __builtin_amdgcn_s_setprio(0);                                         \
    }                                                                        \
    asm volatile("s_waitcnt lgkmcnt(0)" ::: "memory");                       \
    __builtin_amdgcn_sched_barrier(0);                                       \
    BAR();                                                                   \
    if ((t) < 14) STAGE256(CA, CB, ((t) + 2) * 64);                          \
  } while (0)

  STAGE256(sA0, sB0, 0);
  STAGE256(sA1, sB1, 64);

#pragma unroll 1
  for (int tt = 0; tt < 8; ++tt) {
    KSTEP256(sA0, sB0, tt * 2);
    KSTEP256(sA1, sB1, tt * 2 + 1);
  }

  const int epi = D.epi;
#pragma unroll
  for (int mi = 0; mi < 8; ++mi)
#pragma unroll
    for (int ni = 0; ni < 4; ++ni) {
      int col = n0 + wn * 64 + ni * 16 + lr;
#pragma unroll
      for (int r = 0; r < 4; ++r) {
        int row = m0 + wm * 128 + mi * 16 + hi4 * 4 + r;
        float v = acc[mi][ni][r];
        if (epi) v = v / (1.f + __expf(-v));
        D.C[(size_t)row * C_ + col] = v;
      }
    }
#undef KSTEP256
#undef STAGE256
}

// ---------------- fused data-dependent mix (5 outputs, x/xx staged once) ---
struct MixArgs { const float* tm[5]; ushort_t* dst[5]; };

__global__ __launch_bounds__(256) void fused_mix(
    const float* __restrict__ x, const float* __restrict__ xx,
    const ushort_t* __restrict__ t5, const ushort_t* __restrict__ w2t,
    MixArgs margs) {
  __shared__ float xs[64 * 128];
  __shared__ float xxs[64 * 128];
  __shared__ ushort_t sA[64 * 32];
  __shared__ ushort_t sB[128 * 32];
  const int t = threadIdx.x;
  const int l = t & 63;
  const int w = t >> 6;
  const int wm = w >> 1, wn = w & 1;
  const int m0 = blockIdx.x * 64, n0 = blockIdx.y * 128;
  const int lr = l & 15;
  const int lk = (l >> 4) * 8;

#pragma unroll
  for (int it = 0; it < 8; ++it) {
    int row = it * 8 + (t >> 5);
    int c16 = t & 31;
    gload16(x + (size_t)(m0 + row) * C_ + n0 + c16 * 4, (char*)xs + row * 512 + c16 * 16);
    gload16(xx + (size_t)(m0 + row) * C_ + n0 + c16 * 4, (char*)xxs + row * 512 + c16 * 16);
  }

  for (int f = 0; f < 5; ++f) {
    __syncthreads();
    {
      int row = t >> 2, c8 = t & 3;
      gload16(t5 + (size_t)(m0 + row) * 256 + f * 32 + c8 * 8, (char*)sA + t * 16);
    }
#pragma unroll
    for (int it = 0; it < 2; ++it) {
      int row = it * 64 + (t >> 2), c8 = t & 3;
      gload16(w2t + (size_t)(n0 + row) * 160 + f * 32 + c8 * 8,
              (char*)sB + it * 4096 + t * 16);
    }
    __syncthreads();
    bf16x8 af[2], bfr[4];
#pragma unroll
    for (int mi = 0; mi < 2; ++mi)
      af[mi] = *(const bf16x8*)&sA[(wm * 32 + mi * 16 + lr) * 32 + lk];
#pragma unroll
    for (int ni = 0; ni < 4; ++ni)
      bfr[ni] = *(const bf16x8*)&sB[(wn * 64 + ni * 16 + lr) * 32 + lk];
    f32x4 acc[2][4] = {};
#pragma unroll
    for (int mi = 0; mi < 2; ++mi)
#pragma unroll
      for (int ni = 0; ni < 4; ++ni)
        acc[mi][ni] = __builtin_amdgcn_mfma_f32_16x16x32_bf16(af[mi], bfr[ni], acc[mi][ni], 0, 0, 0);
    const float* tmf = margs.tm[f];
    ushort_t* dst = margs.dst[f];
#pragma unroll
    for (int mi = 0; mi < 2; ++mi) {
#pragma unroll
      for (int ni = 0; ni < 4; ++ni) {
        int cl = wn * 64 + ni * 16 + lr;
        int col = n0 + cl;
        float tmv = tmf[col];
#pragma unroll
        for (int r = 0; r < 4; ++r) {
          int rl = wm * 32 + mi * 16 + (l >> 4) * 4 + r;
          int row = m0 + rl;
          float xv = xs[rl * 128 + cl];
          float xxv = xxs[rl * 128 + cl];
          dst[(size_t)row * C_ + col] = f2bf(xv + xxv * (tmv + acc[mi][ni][r]));
        }
      }
    }
  }
}

// ---------------- K1: chunk-local MFMA scan --------------------------------
__global__ __launch_bounds__(256) void chunk_local(
    const float* __restrict__ rx, const float* __restrict__ kx,
    const float* __restrict__ vx, const float* __restrict__ lamx,
    const float* __restrict__ u, float* __restrict__ Mt,
    float* __restrict__ aLg, ushort_t* __restrict__ rAg,
    float* __restrict__ yo) {
  int c = blockIdx.x, bh = blockIdx.y;
  int b = bh >> 4, h = bh & 15;
  __shared__ ushort_t sRA[64 * 64], sKA[64 * 64], sKh[64 * 64], sKl[64 * 64],
                      sVh[64 * 64], sVl[64 * 64], sP[64 * 64];
  __shared__ float qsum[4][64];
  __shared__ float ruk[64];
  const int tid = threadIdx.x;
  const int i = tid & 63;       // channel lane
  const int q = tid >> 6;       // t-quarter
  size_t base = ((size_t)b * T_ + (size_t)c * CHL) * C_ + h * 64;
  size_t cb = ((size_t)c * 32 + bh);

  // ---- phase A: lambda cumsum + tile builds ----
  float lam[16];
  float run = 0.f;
#pragma unroll
  for (int s = 0; s < 16; ++s) {
    lam[s] = lamx[base + (size_t)(q * 16 + s) * C_ + i];
    run += lam[s];
  }
  qsum[q][i] = run;
  __syncthreads();
  float pre = 0.f, ct = 0.f;
#pragma unroll
  for (int qq = 0; qq < 4; ++qq) {
    float vq = qsum[qq][i];
    ct += vq;
    if (qq < q) pre += vq;
  }
  float uu = u[h * 64 + i];
  float ci = pre;
#pragma unroll
  for (int s = 0; s < 16; ++s) {
    int t = q * 16 + s;
    ci += lam[s];
    float cl = ci - lam[s];
    size_t o = base + (size_t)t * C_ + i;
    float rv = rx[o], kv = kx[o], vv = vx[o];
    ushort_t ra = f2bf(rv * __expf(-cl));
    stb(sRA, t, i, ra);
    rAg[cb * 4096 + t * 64 + i] = ra;
    stb(sKA, t, i, f2bf(kv * __expf(ci)));
    float kal = kv * __expf(ci - ct);
    ushort_t khv = f2bf(kal);
    stb(sKh, i, t, khv);
    stb(sKl, i, t, f2bf(kal - bf2f(khv)));
    ushort_t vhv = f2bf(vv);
    stb(sVh, i, t, vhv);
    stb(sVl, i, t, f2bf(vv - bf2f(vhv)));
    float rr = rv * uu * kv;
#pragma unroll
    for (int m = 32; m; m >>= 1) rr += __shfl_xor(rr, m);
    if (i == 0) ruk[t] = rr;
  }
  if (q == 0) aLg[cb * 64 + i] = __expf(-ct);
  __syncthreads();

  const int l = tid & 63, w = tid >> 6;
  const int wm = w >> 1, wn = w & 1;
  const int lr = l & 15, hi4 = l >> 4;

  // ---- phase B: P = rA @ kA^T, mask, store bf16 ----
  {
    f32x4 accP[2][2] = {};
#pragma unroll
    for (int kk = 0; kk < 2; ++kk) {
      bf16x8 af[2], bf_[2];
#pragma unroll
      for (int mi = 0; mi < 2; ++mi) af[mi] = ldb(sRA, wm * 32 + mi * 16 + lr, kk * 64 + hi4 * 16);
#pragma unroll
      for (int ni = 0; ni < 2; ++ni) bf_[ni] = ldb(sKA, wn * 32 + ni * 16 + lr, kk * 64 + hi4 * 16);
#pragma unroll
      for (int mi = 0; mi < 2; ++mi)
#pragma unroll
        for (int ni = 0; ni < 2; ++ni)
          accP[mi][ni] = __builtin_amdgcn_mfma_f32_16x16x32_bf16(af[mi], bf_[ni], accP[mi][ni], 0, 0, 0);
    }
#pragma unroll
    for (int mi = 0; mi < 2; ++mi)
#pragma unroll
      for (int ni = 0; ni < 2; ++ni)
#pragma unroll
        for (int r = 0; r < 4; ++r) {
          int tl = wm * 32 + mi * 16 + hi4 * 4 + r, sl = wn * 32 + ni * 16 + lr;
          float v = accP[mi][ni][r];
          v = sl < tl ? v : (sl == tl ? ruk[tl] : 0.f);
          stb(sP, tl, sl, f2bf(v));
        }
  }
  __syncthreads();

  // ---- phase C: y_intra = P@(Vh+Vl);  Mt = (Vh+Vl)^T @ (kh+kl) ----
  f32x4 accY[2][2] = {}, accM[2][2] = {};
#pragma unroll
  for (int kk = 0; kk < 2; ++kk) {
    bf16x8 pa[2], vhA[2], vlA[2], vhB[2], vlB[2], khB[2], klB[2];
#pragma unroll
    for (int mi = 0; mi < 2; ++mi) {
      int rw = wm * 32 + mi * 16 + lr;
      pa[mi] = ldb(sP, rw, kk * 64 + hi4 * 16);
      vhA[mi] = ldb(sVh, rw, kk * 64 + hi4 * 16);
      vlA[mi] = ldb(sVl, rw, kk * 64 + hi4 * 16);
    }
#pragma unroll
    for (int ni = 0; ni < 2; ++ni) {
      int rw = wn * 32 + ni * 16 + lr;
      vhB[ni] = ldb(sVh, rw, kk * 64 + hi4 * 16);
      vlB[ni] = ldb(sVl, rw, kk * 64 + hi4 * 16);
      khB[ni] = ldb(sKh, rw, kk * 64 + hi4 * 16);
      klB[ni] = ldb(sKl, rw, kk * 64 + hi4 * 16);
    }
#pragma unroll
    for (int mi = 0; mi < 2; ++mi)
#pragma unroll
      for (int ni = 0; ni < 2; ++ni) {
        accY[mi][ni] = __builtin_amdgcn_mfma_f32_16x16x32_bf16(pa[mi], vhB[ni], accY[mi][ni], 0, 0, 0);
        accY[mi][ni] = __builtin_amdgcn_mfma_f32_16x16x32_bf16(pa[mi], vlB[ni], accY[mi][ni], 0, 0, 0);
        accM[mi][ni] = __builtin_amdgcn_mfma_f32_16x16x32_bf16(vhA[mi], khB[ni], accM[mi][ni], 0, 0, 0);
        accM[mi][ni] = __builtin_amdgcn_mfma_f32_16x16x32_bf16(vhA[mi], klB[ni], accM[mi][ni], 0, 0, 0);
        accM[mi][ni] = __builtin_amdgcn_mfma_f32_16x16x32_bf16(vlA[mi], khB[ni], accM[mi][ni], 0, 0, 0);
      }
  }
#pragma unroll
  for (int mi = 0; mi < 2; ++mi)
#pragma unroll
    for (int ni = 0; ni < 2; ++ni)
#pragma unroll
      for (int r = 0; r < 4; ++r) {
        int rw = wm * 32 + mi * 16 + hi4 * 4 + r;
        int cw = wn * 32 + ni * 16 + lr;
        yo[base + (size_t)rw * C_ + cw] = accY[mi][ni][r];     // y_intra[t][j]
        Mt[cb * 4096 + rw * 64 + cw] = accM[mi][ni][r];        // Mt[j][i]
      }
}

// ---------------- K2: sequential chunk combine (vec4, S0 bf16 hi/lo) -------
__global__ __launch_bounds__(256) void combine2(
    const float* __restrict__ Mt, const float* __restrict__ aLg,
    ushort_t* __restrict__ S0h, ushort_t* __restrict__ S0l) {
  int bh = blockIdx.x >> 2;
  int ij = ((blockIdx.x & 3) * 256 + threadIdx.x) * 4;   // [j][i] linear, 4-wide
  int i = ij & 63;
  float4 s = {0.f, 0.f, 0.f, 0.f};
  for (int c = 0; c < NCH; ++c) {
    size_t o = ((size_t)c * 32 + bh) * 4096 + ij;
    float4 m = *(const float4*)&Mt[o];
    float4 p = *(const float4*)&aLg[((size_t)c * 32 + bh) * 64 + i];
    ushort4 hi, lo;
    hi.x = f2bf(s.x); lo.x = f2bf(s.x - bf2f(hi.x));
    hi.y = f2bf(s.y); lo.y = f2bf(s.y - bf2f(hi.y));
    hi.z = f2bf(s.z); lo.z = f2bf(s.z - bf2f(hi.z));
    hi.w = f2bf(s.w); lo.w = f2bf(s.w - bf2f(hi.w));
    *(ushort4*)&S0h[o] = hi;
    *(ushort4*)&S0l[o] = lo;
    s.x = p.x * s.x + m.x; s.y = p.y * s.y + m.y;
    s.z = p.z * s.z + m.z; s.w = p.w * s.w + m.w;
  }
}

// ---------------- K3: y = y_intra + rA@S0, GroupNorm, *g -> bf16 Z ---------
__global__ __launch_bounds__(256) void inter_gn(
    const ushort_t* __restrict__ rAg, const ushort_t* __restrict__ S0h,
    const ushort_t* __restrict__ S0l, const float* __restrict__ yin,
    const float* __restrict__ gx, const float* __restrict__ lnw,
    const float* __restrict__ lnb, ushort_t* __restrict__ Z) {
  int c = blockIdx.x, bh = blockIdx.y;
  int b = bh >> 4, h = bh & 15;
  __shared__ ushort_t sRA[64 * 64], sSh[64 * 64], sSl[64 * 64];
  __shared__ float st[64][2][2];
  const int tid = threadIdx.x;
  size_t cb = ((size_t)c * 32 + bh) * 4096;
#pragma unroll
  for (int it = 0; it < 2; ++it) {
    int lb = tid * 32 + it * 16;
    int row = lb >> 7, wi = lb & 127;
    int so = row * 128 + (wi ^ ((row & 7) << 4));
    *(uint4*)((char*)sRA + so) = *(const uint4*)((const char*)(rAg + cb) + lb);
    *(uint4*)((char*)sSh + so) = *(const uint4*)((const char*)(S0h + cb) + lb);
    *(uint4*)((char*)sSl + so) = *(const uint4*)((const char*)(S0l + cb) + lb);
  }
  const int l = tid & 63, w = tid >> 6;
  const int wm = w >> 1, wn = w & 1;
  const int lr = l & 15, hi4 = l >> 4;
  size_t base = ((size_t)b * T_ + (size_t)c * CHL) * C_ + h * 64;

  f32x4 acc[2][2];
#pragma unroll
  for (int mi = 0; mi < 2; ++mi)
#pragma unroll
    for (int ni = 0; ni < 2; ++ni)
#pragma unroll
      for (int r = 0; r < 4; ++r)
        acc[mi][ni][r] = yin[base + (size_t)(wm * 32 + mi * 16 + hi4 * 4 + r) * C_ +
                             wn * 32 + ni * 16 + lr];
  __syncthreads();
#pragma unroll
  for (int kk = 0; kk < 2; ++kk) {
    bf16x8 af[2], bh_[2], bl_[2];
#pragma unroll
    for (int mi = 0; mi < 2; ++mi) af[mi] = ldb(sRA, wm * 32 + mi * 16 + lr, kk * 64 + hi4 * 16);
#pragma unroll
    for (int ni = 0; ni < 2; ++ni) {
      bh_[ni] = ldb(sSh, wn * 32 + ni * 16 + lr, kk * 64 + hi4 * 16);
      bl_[ni] = ldb(sSl, wn * 32 + ni * 16 + lr, kk * 64 + hi4 * 16);
    }
#pragma unroll
    for (int mi = 0; mi < 2; ++mi)
#pragma unroll
      for (int ni = 0; ni < 2; ++ni) {
        acc[mi][ni] = __builtin_amdgcn_mfma_f32_16x16x32_bf16(af[mi], bh_[ni], acc[mi][ni], 0, 0, 0);
        acc[mi][ni] = __builtin_amdgcn_mfma_f32_16x16x32_bf16(af[mi], bl_[ni], acc[mi][ni], 0, 0, 0);
      }
  }
#pragma unroll
  for (int mi = 0; mi < 2; ++mi)
#pragma unroll
    for (int r = 0; r < 4; ++r) {
      int row = wm * 32 + mi * 16 + hi4 * 4 + r;
      float s1 = acc[mi][0][r] + acc[mi][1][r];
      float s2 = acc[mi][0][r] * acc[mi][0][r] + acc[mi][1][r] * acc[mi][1][r];
#pragma unroll
      for (int m = 1; m < 16; m <<= 1) { s1 += __shfl_xor(s1, m); s2 += __shfl_xor(s2, m); }
      if (lr == 0) { st[row][wn][0] = s1; st[row][wn][1] = s2; }
    }
  __syncthreads();
#pragma unroll
  for (int mi = 0; mi < 2; ++mi)
#pragma unroll
    for (int ni = 0; ni < 2; ++ni)
#pragma unroll
      for (int r = 0; r < 4; ++r) {
        int row = wm * 32 + mi * 16 + hi4 * 4 + r;
        int jl = wn * 32 + ni * 16 + lr;
        float S1 = st[row][0][0] + st[row][1][0];
        float S2 = st[row][0][1] + st[row][1][1];
        float mu = S1 * (1.f / 64.f);
        float var = S2 * (1.f / 64.f) - mu * mu;
        float rs = rsqrtf(var + 6.4e-4f);          // EPS = 1e-5 * 64
        int col = h * 64 + jl;
        size_t o = base + (size_t)row * C_ + jl;
        float yn = (acc[mi][ni][r] - mu) * rs * lnw[col] + lnb[col];
        Z[o] = f2bf(yn * gx[o]);
      }
}

// ===========================================================================
extern "C" void kernel_launch(void* const* d_in, const int* in_sizes, int n_in,
                              void* d_out, int out_size, void* d_ws, size_t ws_size,
                              hipStream_t stream) {
  const float* x    = (const float*)d_in[0];
  const float* tmx  = (const float*)d_in[1];
  const float* tmw  = (const float*)d_in[2];
  const float* tmk  = (const float*)d_in[3];
  const float* tmv  = (const float*)d_in[4];
  const float* tmr  = (const float*)d_in[5];
  const float* tmg  = (const float*)d_in[6];
  const float* maaw1 = (const float*)d_in[7];
  const float* maaw2 = (const float*)d_in[8];
  const float* tdec = (const float*)d_in[9];
  const float* tdw1 = (const float*)d_in[10];
  const float* tdw2 = (const float*)d_in[11];
  const float* u    = (const float*)d_in[12];
  const float* Wr   = (const float*)d_in[13];
  const float* Wk   = (const float*)d_in[14];
  const float* Wv   = (const float*)d_in[15];
  const float* Wg   = (const float*)d_in[16];
  const float* Wo   = (const float*)d_in[17];
  const float* lnw  = (const float*)d_in[18];
  const float* lnb  = (const float*)d_in[19];

  char* ws = (char*)d_ws;
  const size_t MB = 1ull << 20;
  float*    xx     = (float*)(ws + 0);            // 16MB (later: yb)
  ushort_t* xxx    = (ushort_t*)(ws + 16 * MB);   // 8MB  (later: Zb)
  ushort_t* WrT    = (ushort_t*)(ws + 24 * MB);
  ushort_t* WkT    = (ushort_t*)(ws + 26 * MB);
  ushort_t* WvT    = (ushort_t*)(ws + 28 * MB);
  ushort_t* WgT    = (ushort_t*)(ws + 30 * MB);
  ushort_t* WoT    = (ushort_t*)(ws + 32 * MB);
  ushort_t* maaW1T = (ushort_t*)(ws + 34 * MB);              // 256x1024
  ushort_t* tdW1T  = (ushort_t*)(ws + 35 * MB);              // 128x1024
  ushort_t* tdW2T  = (ushort_t*)(ws + 35 * MB + 256 * 1024); // 1024x64
  ushort_t* maaW2T = (ushort_t*)(ws + 35 * MB + 512 * 1024); // 1024x160
  ushort_t* t5     = (ushort_t*)(ws + 36 * MB);   // 4096x256 bf16
  ushort_t* t5d    = (ushort_t*)(ws + 38 * MB);   // 4096x128 bf16
  ushort_t* Xm[5];
  for (int f = 0; f < 5; ++f) Xm[f] = (ushort_t*)(ws + 40 * MB + (size_t)f * 8 * MB);
  float*    Mtb = (float*)(ws + 40 * MB);          // 16MB  (over Xm[0..1], dead)
  ushort_t* S0h = (ushort_t*)(ws + 56 * MB);       // 8MB   (over Xm[2])
  ushort_t* S0l = (ushort_t*)(ws + 64 * MB);       // 8MB   (over Xm[3])
  ushort_t* rAg = (ushort_t*)(ws + 72 * MB);       // 8MB   (over Xm[4])
  float* rb   = (float*)(ws + 80 * MB);
  float* kb   = (float*)(ws + 96 * MB);
  float* vb   = (float*)(ws + 112 * MB);
  float* gb   = (float*)(ws + 128 * MB);
  float* lam  = (float*)(ws + 144 * MB);
  float* aLg  = (float*)(ws + 160 * MB);           // 256KB
  float* yb   = (float*)(ws + 0);                  // alias xx (dead by then)
  ushort_t* Zb = (ushort_t*)(ws + 16 * MB);        // alias xxx (dead by then)

  // 1) weight transposes/converts
  TArgs ta;
  ta.d[0] = TDesc{Wr,    WrT,    1024, 1024, 1024};
  ta.d[1] = TDesc{Wk,    WkT,    1024, 1024, 1024};
  ta.d[2] = TDesc{Wv,    WvT,    1024, 1024, 1024};
  ta.d[3] = TDesc{Wg,    WgT,    1024, 1024, 1024};
  ta.d[4] = TDesc{Wo,    WoT,    1024, 1024, 1024};
  ta.d[5] = TDesc{maaw1, maaW1T, 1024, 160,  256};
  ta.d[6] = TDesc{tdw1,  tdW1T,  1024, 64,   128};
  ta.d[7] = TDesc{tdw2,  tdW2T,  64,   1024, 1024};
  ta.d[8] = TDesc{maaw2, maaW2T, 160,  1024, 1024};
  transpose_cvt<<<dim3(32, 32, 9), 256, 0, stream>>>(ta);

  // 2) token shift + base mix
  prep_kernel<<<(B_ * T_ * C_) / 1024, 256, 0, stream>>>(x, tmx, xx, xxx);

  // 3) t5 = tanh(xxx @ maa_w1)  (64-row tiles: 128 blocks)
  gemm_bt64<<<dim3(64, 2), 256, 0, stream>>>(xxx, C_, maaW1T, C_, t5, 256, C_);

  // 4) fused per-f mix
  MixArgs ma;
  ma.tm[0] = tmw; ma.tm[1] = tmk; ma.tm[2] = tmv; ma.tm[3] = tmr; ma.tm[4] = tmg;
  for (int f = 0; f < 5; ++f) ma.dst[f] = Xm[f];
  fused_mix<<<dim3(64, 8), 256, 0, stream>>>(x, xx, t5, maaW2T, ma);

  // 5) projections r,k,v,g — 256² pipelined, 256 blocks (1/CU)
  PArgs pa;
  pa.d[0] = PDesc{Xm[3], WrT, rb, 0};
  pa.d[1] = PDesc{Xm[1], WkT, kb, 0};
  pa.d[2] = PDesc{Xm[2], WvT, vb, 0};
  pa.d[3] = PDesc{Xm[4], WgT, gb, 1};
  gemm_proj256<<<dim3(16, 4, 4), 512, 0, stream>>>(pa);

  // 6) decay: t5d = tanh(xw @ td_w1); lam = exp(tdecay + t5d @ td_w2)
  gemm_bt64<<<dim3(64, 1), 256, 0, stream>>>(Xm[0], C_, tdW1T, C_, t5d, 128, C_);
  gemm_bt<4><<<dim3(32, 8), 256, 0, stream>>>(t5d, 128, tdW2T, 64, lam, C_, 64, tdec);

  // 7) MFMA chunked scan
  chunk_local<<<dim3(NCH, B_ * H_), 256, 0, stream>>>(rb, kb, vb, lam, u, Mtb, aLg, rAg, yb);
  combine2<<<128, 256, 0, stream>>>(Mtb, aLg, S0h, S0l);
  inter_gn<<<dim3(NCH, B_ * H_), 256, 0, stream>>>(rAg, S0h, S0l, yb, gb, lnw, lnb, Zb);

  // 8) out = Z @ Wo
  gemm_bt<0><<<dim3(32, 8), 256, 0, stream>>>(Zb, C_, WoT, C_, (float*)d_out, C_, C_, nullptr);
}